// Round 1
// baseline (2474.566 us; speedup 1.0000x reference)
//
#include <hip/hip_runtime.h>
#include <math.h>

#define NUSER 10000
#define NITEM 30000
#define NN    40000
#define DD    64

__device__ __forceinline__ float wsum(float v) {
#pragma unroll
    for (int o = 32; o > 0; o >>= 1) v += __shfl_xor(v, o, 64);
    return v;
}

// ---------------- CSR build ----------------
__global__ void k_hist(const int* ei, int E2, int E, int* cnt) {
    int i = blockIdx.x * blockDim.x + threadIdx.x;
    if (i >= E2) return;
    int d = (i < E) ? ei[E + i] : ei[i - E];
    atomicAdd(&cnt[d], 1);
}

__global__ void k_scan(const int* cnt, int* rp, int n) {
    __shared__ int buf[1024];
    __shared__ int carry;
    int t = threadIdx.x;
    if (t == 0) carry = 0;
    __syncthreads();
    for (int base = 0; base < n; base += 1024) {
        int i = base + t;
        int v = (i < n) ? cnt[i] : 0;
        int x = v;
        buf[t] = x;
        __syncthreads();
        for (int o = 1; o < 1024; o <<= 1) {
            int y = (t >= o) ? buf[t - o] : 0;
            __syncthreads();
            x += y;
            buf[t] = x;
            __syncthreads();
        }
        if (i < n) rp[i] = carry + x - v;
        __syncthreads();
        if (t == 1023) carry += x;
        __syncthreads();
    }
    if (t == 0) rp[n] = carry;
}

__global__ void k_scatter(const int* ei, int E2, int E, const int* rp, int* fill, int* col) {
    int i = blockIdx.x * blockDim.x + threadIdx.x;
    if (i >= E2) return;
    int j = (i < E) ? i : i - E;
    int s = (i < E) ? ei[j] : ei[E + j];
    int d = (i < E) ? ei[E + j] : ei[j];
    int pos = rp[d] + atomicAdd(&fill[d], 1);
    col[pos] = s;
}

// ---------------- node prep ----------------
__global__ void k_l2rows(const float* __restrict__ in, float* __restrict__ out, int rows) {
    int t = blockIdx.x * blockDim.x + threadIdx.x;
    int w = t >> 6, lane = t & 63, nw = (gridDim.x * blockDim.x) >> 6;
    for (int r = w; r < rows; r += nw) {
        float v = in[(size_t)r * DD + lane];
        float n = sqrtf(wsum(v * v));
        out[(size_t)r * DD + lane] = v / fmaxf(n, 1e-12f);
    }
}

template <int K>
__global__ void k_mlp(const float* __restrict__ feat, const float* __restrict__ W,
                      const float* __restrict__ bias, float* __restrict__ out, int rows) {
    __shared__ float Wl[K][DD];
    __shared__ float rbuf[4][K];
    int t = threadIdx.x;
    for (int i = t; i < DD * K; i += 256) {
        int c = i / K, k = i - c * K;
        Wl[k][c] = W[i];
    }
    __syncthreads();
    int wib = t >> 6, lane = t & 63;
    float b = bias[lane];
    for (int r = blockIdx.x * 4 + wib; r < rows; r += gridDim.x * 4) {
        for (int k = lane; k < K; k += 64) rbuf[wib][k] = feat[(size_t)r * K + k];
        asm volatile("s_waitcnt lgkmcnt(0)" ::: "memory");
        float acc = b;
#pragma unroll 4
        for (int k = 0; k < K; k++) acc += rbuf[wib][k] * Wl[k][lane];
        float h = acc > 0.f ? acc : 0.01f * acc;
        float n = sqrtf(wsum(h * h));
        out[(size_t)r * DD + lane] = h / fmaxf(n, 1e-12f);
    }
}

// ---------------- 64x64 GEMM: out = x @ W ----------------
__global__ void k_gemm64(const float* __restrict__ x, const float* __restrict__ W,
                         float* __restrict__ out, int rows) {
    __shared__ float Wl[DD][DD];  // Wl[k][c]
    __shared__ float rbuf[4][DD];
    int t = threadIdx.x;
    for (int i = t; i < DD * DD; i += 256) Wl[i >> 6][i & 63] = W[i];
    __syncthreads();
    int wib = t >> 6, lane = t & 63;
    for (int r = blockIdx.x * 4 + wib; r < rows; r += gridDim.x * 4) {
        rbuf[wib][lane] = x[(size_t)r * DD + lane];
        asm volatile("s_waitcnt lgkmcnt(0)" ::: "memory");
        float acc = 0.f;
#pragma unroll 8
        for (int k = 0; k < DD; k++) acc += rbuf[wib][k] * Wl[k][lane];
        out[(size_t)r * DD + lane] = acc;
    }
}

// ---------------- GAT convs (one wave per dst node, online softmax) ----------------
__global__ void k_gat_ori(const float* __restrict__ h, const int* __restrict__ rp,
                          const int* __restrict__ col, float* __restrict__ out) {
    int t = blockIdx.x * blockDim.x + threadIdx.x;
    int w = t >> 6, lane = t & 63, nw = (gridDim.x * blockDim.x) >> 6;
    for (int n = w; n < NN; n += nw) {
        float hd = h[(size_t)n * DD + lane];
        int e0 = rp[n], e1 = rp[n + 1];
        float m = -INFINITY, s = 0.f, acc = 0.f;
        for (int e = e0; e < e1; e++) {
            int sn = col[e];
            float hs = h[(size_t)sn * DD + lane];
            float d = wsum(hd * hs);
            float sc = d > 0.f ? d : 0.2f * d;
            float mn = fmaxf(m, sc);
            float scale = __expf(m - mn);
            float p = __expf(sc - mn);
            s = s * scale + p;
            acc = acc * scale + p * hs;
            m = mn;
        }
        out[(size_t)n * DD + lane] = acc / (s + 1e-16f);
    }
}

__global__ void k_gat_pre(const float* __restrict__ hx, const float* __restrict__ y,
                          const float* __restrict__ z, const int* __restrict__ rp,
                          const int* __restrict__ col, float* __restrict__ out) {
    int t = blockIdx.x * blockDim.x + threadIdx.x;
    int w = t >> 6, lane = t & 63, nw = (gridDim.x * blockDim.x) >> 6;
    for (int n = w; n < NN; n += nw) {
        float hd = hx[(size_t)n * DD + lane];
        float yd = y[(size_t)n * DD + lane];
        float zd = z[(size_t)n * DD + lane];
        int e0 = rp[n], e1 = rp[n + 1];
        float m = -INFINITY, s = 0.f, acc = 0.f;
        for (int e = e0; e < e1; e++) {
            int sn = col[e];
            float hs = hx[(size_t)sn * DD + lane];
            float ys = y[(size_t)sn * DD + lane];
            float zs = z[(size_t)sn * DD + lane];
            float a = hd * hs, b = yd * ys, c = zd * zs;
#pragma unroll
            for (int o = 32; o > 0; o >>= 1) {
                a += __shfl_xor(a, o, 64);
                b += __shfl_xor(b, o, 64);
                c += __shfl_xor(c, o, 64);
            }
            float sc = a > 0.f ? a : 0.2f * a;
            float gate = 1.f / (1.f + __expf(-0.5f * (b + c)));
            float g = gate > 0.5f ? gate : 1.f;
            float mn = fmaxf(m, sc);
            float scale = __expf(m - mn);
            float p = __expf(sc - mn);
            s = s * scale + p;
            acc = acc * scale + p * g * hs;
            m = mn;
        }
        out[(size_t)n * DD + lane] = acc / (s + 1e-16f);
    }
}

__global__ void k_gcn(const float* __restrict__ h, const int* __restrict__ rp,
                      const int* __restrict__ col, float* __restrict__ out, int leaky) {
    int t = blockIdx.x * blockDim.x + threadIdx.x;
    int w = t >> 6, lane = t & 63, nw = (gridDim.x * blockDim.x) >> 6;
    for (int n = w; n < NN; n += nw) {
        int e0 = rp[n], e1 = rp[n + 1];
        float acc = 0.f;
        for (int e = e0; e < e1; e++) {
            int sn = col[e];
            acc += h[(size_t)sn * DD + lane];
        }
        if (leaky) acc = acc > 0.f ? acc : 0.01f * acc;
        out[(size_t)n * DD + lane] = acc;
    }
}

// out[r*ostride + lane] = l2norm(x[r] + g[r])
__global__ void k_addl2(const float* __restrict__ x, const float* __restrict__ g,
                        float* __restrict__ out, int ostride, int rows) {
    int t = blockIdx.x * blockDim.x + threadIdx.x;
    int w = t >> 6, lane = t & 63, nw = (gridDim.x * blockDim.x) >> 6;
    for (int r = w; r < rows; r += nw) {
        float v = x[(size_t)r * DD + lane] + g[(size_t)r * DD + lane];
        float n = sqrtf(wsum(v * v));
        out[(size_t)r * ostride + lane] = v / fmaxf(n, 1e-12f);
    }
}

__global__ void k_final(const float* __restrict__ x0, const float* __restrict__ h1,
                        const float* __restrict__ h2, const float* __restrict__ h3,
                        float* __restrict__ out) {
    int i = blockIdx.x * blockDim.x + threadIdx.x;
    if (i >= NN * DD) return;
    int r = i >> 6, lane = i & 63;
    out[(size_t)r * 256 + lane] = x0[i] + h1[i] + h2[i] + h3[i];
}

extern "C" void kernel_launch(void* const* d_in, const int* in_sizes, int n_in,
                              void* d_out, int out_size, void* d_ws, size_t ws_size,
                              hipStream_t stream) {
    const int* ei       = (const int*)d_in[0];
    const float* v_feat = (const float*)d_in[1];
    const float* a_feat = (const float*)d_in[2];
    const float* t_feat = (const float*)d_in[3];
    const float* pref_v = (const float*)d_in[4];
    const float* pref_a = (const float*)d_in[5];
    const float* pref_t = (const float*)d_in[6];
    const float* mlp_v_w = (const float*)d_in[7];
    const float* mlp_v_b = (const float*)d_in[8];
    const float* mlp_a_w = (const float*)d_in[9];
    const float* mlp_a_b = (const float*)d_in[10];
    const float* mlp_t_w = (const float*)d_in[11];
    const float* mlp_t_b = (const float*)d_in[12];
    const float* pre_w  = (const float*)d_in[13];
    const float* ori_w  = (const float*)d_in[14];
    const float* gcn_w  = (const float*)d_in[15];
    const float* id_emb = (const float*)d_in[16];
    float* out = (float*)d_out;

    const int E2 = in_sizes[0] / 1;   // total int elements = 2*E
    const int E  = E2 / 2;

    char* w = (char*)d_ws;
    auto alloc = [&](size_t bytes) -> void* {
        void* p = (void*)w;
        w += (bytes + 255) & ~(size_t)255;
        return p;
    };
    int* cnt = (int*)alloc((size_t)NN * 4);
    int* rp  = (int*)alloc((size_t)(NN + 1) * 4);
    int* col = (int*)alloc((size_t)E2 * 4);
    float* Mv = (float*)alloc((size_t)NN * DD * 4);
    float* Ma = (float*)alloc((size_t)NN * DD * 4);
    float* Mt = (float*)alloc((size_t)NN * DD * 4);
    float* xb = (float*)alloc((size_t)NN * DD * 4);
    float* hb = (float*)alloc((size_t)NN * DD * 4);
    float* gb = (float*)alloc((size_t)NN * DD * 4);

    // ---- CSR by destination ----
    hipMemsetAsync(cnt, 0, (size_t)NN * 4, stream);
    k_hist<<<(E2 + 255) / 256, 256, 0, stream>>>(ei, E2, E, cnt);
    k_scan<<<1, 1024, 0, stream>>>(cnt, rp, NN);
    hipMemsetAsync(cnt, 0, (size_t)NN * 4, stream);
    k_scatter<<<(E2 + 255) / 256, 256, 0, stream>>>(ei, E2, E, rp, cnt, col);

    // ---- per-modality node features: M = cat(l2norm(pref), l2norm(leaky(feat@W.T+b))) ----
    k_l2rows<<<640, 256, 0, stream>>>(pref_v, Mv, NUSER);
    k_l2rows<<<640, 256, 0, stream>>>(pref_a, Ma, NUSER);
    k_l2rows<<<640, 256, 0, stream>>>(pref_t, Mt, NUSER);
    k_mlp<128><<<512, 256, 0, stream>>>(v_feat, mlp_v_w, mlp_v_b, Mv + (size_t)NUSER * DD, NITEM);
    k_mlp<128><<<512, 256, 0, stream>>>(a_feat, mlp_a_w, mlp_a_b, Ma + (size_t)NUSER * DD, NITEM);
    k_mlp<100><<<512, 256, 0, stream>>>(t_feat, mlp_t_w, mlp_t_b, Mt + (size_t)NUSER * DD, NITEM);

    const float* Ms[3] = {Mv, Ma, Mt};
    const float* Ys[3] = {Ma, Mv, Ma};
    const float* Zs[3] = {Mt, Mt, Mv};
    const int coloff[3] = {64, 128, 192};

    const int GB = (NN + 3) / 4;  // one wave per node
    for (int mo = 0; mo < 3; mo++) {
        // x = l2norm(gat_pre(M, y, z))
        k_gemm64<<<2500, 256, 0, stream>>>(Ms[mo], pre_w + (size_t)mo * 4096, hb, NN);
        k_gat_pre<<<GB, 256, 0, stream>>>(hb, Ys[mo], Zs[mo], rp, col, gb);
        k_l2rows<<<2500, 256, 0, stream>>>(gb, xb, NN);
        for (int it = 0; it < 3; it++) {
            k_gemm64<<<2500, 256, 0, stream>>>(xb, ori_w + (size_t)mo * 4096, hb, NN);
            k_gat_ori<<<GB, 256, 0, stream>>>(hb, rp, col, gb);
            if (it < 2)
                k_addl2<<<2500, 256, 0, stream>>>(xb, gb, xb, DD, NN);
            else
                k_addl2<<<2500, 256, 0, stream>>>(xb, gb, out + coloff[mo], 256, NN);
        }
    }

    // ---- real_gcn (reuse Mv=x0, Ma=h1, Mt=h2, gb=h3) ----
    k_l2rows<<<2500, 256, 0, stream>>>(id_emb, Mv, NN);
    k_gemm64<<<2500, 256, 0, stream>>>(Mv, gcn_w + 0, hb, NN);
    k_gcn<<<GB, 256, 0, stream>>>(hb, rp, col, Ma, 1);
    k_gemm64<<<2500, 256, 0, stream>>>(Ma, gcn_w + 4096, hb, NN);
    k_gcn<<<GB, 256, 0, stream>>>(hb, rp, col, Mt, 1);
    k_gemm64<<<2500, 256, 0, stream>>>(Ma, gcn_w + 8192, hb, NN);
    k_gcn<<<GB, 256, 0, stream>>>(hb, rp, col, gb, 0);
    k_final<<<(NN * DD + 255) / 256, 256, 0, stream>>>(Mv, Ma, Mt, gb, out);
}

// Round 2
// 1448.670 us; speedup vs baseline: 1.7082x; 1.7082x over previous
//
#include <hip/hip_runtime.h>
#include <math.h>

#define NUSER 10000
#define NITEM 30000
#define NN    40000
#define DD    64

__device__ __forceinline__ float wsum(float v) {
#pragma unroll
    for (int o = 32; o > 0; o >>= 1) v += __shfl_xor(v, o, 64);
    return v;
}
// reduce over the 16-lane dim-group (lanes differing in bits 0..3)
__device__ __forceinline__ float qsum16(float v) {
    v += __shfl_xor(v, 1, 64);
    v += __shfl_xor(v, 2, 64);
    v += __shfl_xor(v, 4, 64);
    v += __shfl_xor(v, 8, 64);
    return v;
}
// combine across the 4 edge-groups (bits 4,5)
__device__ __forceinline__ float gsum4(float v) {
    v += __shfl_xor(v, 16, 64);
    v += __shfl_xor(v, 32, 64);
    return v;
}
__device__ __forceinline__ float gmax4(float v) {
    v = fmaxf(v, __shfl_xor(v, 16, 64));
    v = fmaxf(v, __shfl_xor(v, 32, 64));
    return v;
}

// ---------------- CSR build ----------------
__global__ void k_hist(const int* ei, int E2, int E, int* cnt) {
    int i = blockIdx.x * blockDim.x + threadIdx.x;
    if (i >= E2) return;
    int d = (i < E) ? ei[E + i] : ei[i - E];
    atomicAdd(&cnt[d], 1);
}

__global__ void k_scan(const int* cnt, int* rp, int n) {
    __shared__ int buf[1024];
    __shared__ int carry;
    int t = threadIdx.x;
    if (t == 0) carry = 0;
    __syncthreads();
    for (int base = 0; base < n; base += 1024) {
        int i = base + t;
        int v = (i < n) ? cnt[i] : 0;
        int x = v;
        buf[t] = x;
        __syncthreads();
        for (int o = 1; o < 1024; o <<= 1) {
            int y = (t >= o) ? buf[t - o] : 0;
            __syncthreads();
            x += y;
            buf[t] = x;
            __syncthreads();
        }
        if (i < n) rp[i] = carry + x - v;
        __syncthreads();
        if (t == 1023) carry += x;
        __syncthreads();
    }
    if (t == 0) rp[n] = carry;
}

__global__ void k_scatter(const int* ei, int E2, int E, const int* rp, int* fill, int* col) {
    int i = blockIdx.x * blockDim.x + threadIdx.x;
    if (i >= E2) return;
    int j = (i < E) ? i : i - E;
    int s = (i < E) ? ei[j] : ei[E + j];
    int d = (i < E) ? ei[E + j] : ei[j];
    int pos = rp[d] + atomicAdd(&fill[d], 1);
    col[pos] = s;
}

// ---------------- node prep ----------------
__global__ void k_l2rows(const float* __restrict__ in, float* __restrict__ out, int rows) {
    int t = blockIdx.x * blockDim.x + threadIdx.x;
    int w = t >> 6, lane = t & 63, nw = (gridDim.x * blockDim.x) >> 6;
    for (int r = w; r < rows; r += nw) {
        float v = in[(size_t)r * DD + lane];
        float n = sqrtf(wsum(v * v));
        out[(size_t)r * DD + lane] = v / fmaxf(n, 1e-12f);
    }
}

template <int K>
__global__ void k_mlp(const float* __restrict__ feat, const float* __restrict__ W,
                      const float* __restrict__ bias, float* __restrict__ out, int rows) {
    __shared__ float Wl[K][DD];
    __shared__ float rbuf[4][K];
    int t = threadIdx.x;
    for (int i = t; i < DD * K; i += 256) {
        int c = i / K, k = i - c * K;
        Wl[k][c] = W[i];
    }
    __syncthreads();
    int wib = t >> 6, lane = t & 63;
    float b = bias[lane];
    for (int r = blockIdx.x * 4 + wib; r < rows; r += gridDim.x * 4) {
        for (int k = lane; k < K; k += 64) rbuf[wib][k] = feat[(size_t)r * K + k];
        asm volatile("s_waitcnt lgkmcnt(0)" ::: "memory");
        float acc = b;
#pragma unroll 4
        for (int k = 0; k < K; k++) acc += rbuf[wib][k] * Wl[k][lane];
        float h = acc > 0.f ? acc : 0.01f * acc;
        float n = sqrtf(wsum(h * h));
        out[(size_t)r * DD + lane] = h / fmaxf(n, 1e-12f);
    }
}

// ---------------- 64x64 GEMM: out = x @ W ----------------
__global__ void k_gemm64(const float* __restrict__ x, const float* __restrict__ W,
                         float* __restrict__ out, int rows) {
    __shared__ float Wl[DD][DD];  // Wl[k][c]
    __shared__ float rbuf[4][DD];
    int t = threadIdx.x;
    for (int i = t; i < DD * DD; i += 256) Wl[i >> 6][i & 63] = W[i];
    __syncthreads();
    int wib = t >> 6, lane = t & 63;
    for (int r = blockIdx.x * 4 + wib; r < rows; r += gridDim.x * 4) {
        rbuf[wib][lane] = x[(size_t)r * DD + lane];
        asm volatile("s_waitcnt lgkmcnt(0)" ::: "memory");
        float acc = 0.f;
#pragma unroll 8
        for (int k = 0; k < DD; k++) acc += rbuf[wib][k] * Wl[k][lane];
        out[(size_t)r * DD + lane] = acc;
    }
}

// ---------------- per-edge dots of a fixed table: D[e] = dot(T[dst], T[src]) ----------------
__global__ void k_edgedot(const float* __restrict__ T, const int* __restrict__ rp,
                          const int* __restrict__ col, float* __restrict__ D) {
    int t = blockIdx.x * blockDim.x + threadIdx.x;
    int w = t >> 6, lane = t & 63, nw = (gridDim.x * blockDim.x) >> 6;
    int g = lane >> 4, q = lane & 15;
    for (int n = w; n < NN; n += nw) {
        int e0 = rp[n], e1 = rp[n + 1];
        if (e0 == e1) continue;
        float4 td = *(const float4*)(T + (size_t)n * DD + q * 4);
        for (int eb = e0; eb < e1; eb += 4) {
            int e = eb + g;
            int ee = (e < e1) ? e : (e1 - 1);
            int sn = col[ee];
            float4 ts = *(const float4*)(T + (size_t)sn * DD + q * 4);
            float d = td.x * ts.x + td.y * ts.y + td.z * ts.z + td.w * ts.w;
            d = qsum16(d);
            if (q == 0 && e < e1) D[e] = d;
        }
    }
}

// ---------------- GAT ori: 4 edges per wave-iteration, online softmax ----------------
__global__ void k_gat_ori(const float* __restrict__ h, const int* __restrict__ rp,
                          const int* __restrict__ col, float* __restrict__ out) {
    int t = blockIdx.x * blockDim.x + threadIdx.x;
    int w = t >> 6, lane = t & 63, nw = (gridDim.x * blockDim.x) >> 6;
    int g = lane >> 4, q = lane & 15;
    for (int n = w; n < NN; n += nw) {
        int e0 = rp[n], e1 = rp[n + 1];
        float4 hd = *(const float4*)(h + (size_t)n * DD + q * 4);
        float m = -INFINITY, s = 0.f;
        float4 acc = make_float4(0.f, 0.f, 0.f, 0.f);
        for (int eb = e0; eb < e1; eb += 4) {
            int e = eb + g;
            bool act = e < e1;
            int ee = act ? e : (e1 - 1);
            int sn = col[ee];
            float4 hs = *(const float4*)(h + (size_t)sn * DD + q * 4);
            float d = hd.x * hs.x + hd.y * hs.y + hd.z * hs.z + hd.w * hs.w;
            d = qsum16(d);
            float sc = d > 0.f ? d : 0.2f * d;
            sc = act ? sc : -INFINITY;
            float mn = fmaxf(m, gmax4(sc));
            float scale = __expf(m - mn);
            float p = __expf(sc - mn);  // inactive: exp(-inf)=0
            float ps = gsum4(p);
            s = s * scale + ps;
            acc.x = acc.x * scale + p * hs.x;
            acc.y = acc.y * scale + p * hs.y;
            acc.z = acc.z * scale + p * hs.z;
            acc.w = acc.w * scale + p * hs.w;
            m = mn;
        }
        acc.x = gsum4(acc.x);
        acc.y = gsum4(acc.y);
        acc.z = gsum4(acc.z);
        acc.w = gsum4(acc.w);
        float inv = 1.f / (s + 1e-16f);
        if (g == 0) {
            float4 o = make_float4(acc.x * inv, acc.y * inv, acc.z * inv, acc.w * inv);
            *(float4*)(out + (size_t)n * DD + q * 4) = o;
        }
    }
}

// ---------------- GAT pre: gate dots precomputed (Dy, Dz per edge) ----------------
__global__ void k_gat_pre(const float* __restrict__ hx, const float* __restrict__ Dy,
                          const float* __restrict__ Dz, const int* __restrict__ rp,
                          const int* __restrict__ col, float* __restrict__ out) {
    int t = blockIdx.x * blockDim.x + threadIdx.x;
    int w = t >> 6, lane = t & 63, nw = (gridDim.x * blockDim.x) >> 6;
    int g = lane >> 4, q = lane & 15;
    for (int n = w; n < NN; n += nw) {
        int e0 = rp[n], e1 = rp[n + 1];
        float4 hd = *(const float4*)(hx + (size_t)n * DD + q * 4);
        float m = -INFINITY, s = 0.f;
        float4 acc = make_float4(0.f, 0.f, 0.f, 0.f);
        for (int eb = e0; eb < e1; eb += 4) {
            int e = eb + g;
            bool act = e < e1;
            int ee = act ? e : (e1 - 1);
            int sn = col[ee];
            float4 hs = *(const float4*)(hx + (size_t)sn * DD + q * 4);
            float gy = Dy[ee], gz = Dz[ee];
            float d = hd.x * hs.x + hd.y * hs.y + hd.z * hs.z + hd.w * hs.w;
            d = qsum16(d);
            float sc = d > 0.f ? d : 0.2f * d;
            sc = act ? sc : -INFINITY;
            float gate = 1.f / (1.f + __expf(-0.5f * (gy + gz)));
            float gf = gate > 0.5f ? gate : 1.f;
            float mn = fmaxf(m, gmax4(sc));
            float scale = __expf(m - mn);
            float p = __expf(sc - mn);
            float ps = gsum4(p);
            float pg = p * gf;
            s = s * scale + ps;
            acc.x = acc.x * scale + pg * hs.x;
            acc.y = acc.y * scale + pg * hs.y;
            acc.z = acc.z * scale + pg * hs.z;
            acc.w = acc.w * scale + pg * hs.w;
            m = mn;
        }
        acc.x = gsum4(acc.x);
        acc.y = gsum4(acc.y);
        acc.z = gsum4(acc.z);
        acc.w = gsum4(acc.w);
        float inv = 1.f / (s + 1e-16f);
        if (g == 0) {
            float4 o = make_float4(acc.x * inv, acc.y * inv, acc.z * inv, acc.w * inv);
            *(float4*)(out + (size_t)n * DD + q * 4) = o;
        }
    }
}

__global__ void k_gcn(const float* __restrict__ h, const int* __restrict__ rp,
                      const int* __restrict__ col, float* __restrict__ out, int leaky) {
    int t = blockIdx.x * blockDim.x + threadIdx.x;
    int w = t >> 6, lane = t & 63, nw = (gridDim.x * blockDim.x) >> 6;
    int g = lane >> 4, q = lane & 15;
    for (int n = w; n < NN; n += nw) {
        int e0 = rp[n], e1 = rp[n + 1];
        float4 acc = make_float4(0.f, 0.f, 0.f, 0.f);
        for (int eb = e0; eb < e1; eb += 4) {
            int e = eb + g;
            bool act = e < e1;
            int ee = act ? e : (e1 - 1);
            int sn = col[ee];
            float4 hs = *(const float4*)(h + (size_t)sn * DD + q * 4);
            float f = act ? 1.f : 0.f;
            acc.x += f * hs.x;
            acc.y += f * hs.y;
            acc.z += f * hs.z;
            acc.w += f * hs.w;
        }
        acc.x = gsum4(acc.x);
        acc.y = gsum4(acc.y);
        acc.z = gsum4(acc.z);
        acc.w = gsum4(acc.w);
        if (leaky) {
            acc.x = acc.x > 0.f ? acc.x : 0.01f * acc.x;
            acc.y = acc.y > 0.f ? acc.y : 0.01f * acc.y;
            acc.z = acc.z > 0.f ? acc.z : 0.01f * acc.z;
            acc.w = acc.w > 0.f ? acc.w : 0.01f * acc.w;
        }
        if (g == 0) *(float4*)(out + (size_t)n * DD + q * 4) = acc;
    }
}

// out[r*ostride + lane] = l2norm(x[r] + g[r])
__global__ void k_addl2(const float* __restrict__ x, const float* __restrict__ g,
                        float* __restrict__ out, int ostride, int rows) {
    int t = blockIdx.x * blockDim.x + threadIdx.x;
    int w = t >> 6, lane = t & 63, nw = (gridDim.x * blockDim.x) >> 6;
    for (int r = w; r < rows; r += nw) {
        float v = x[(size_t)r * DD + lane] + g[(size_t)r * DD + lane];
        float n = sqrtf(wsum(v * v));
        out[(size_t)r * ostride + lane] = v / fmaxf(n, 1e-12f);
    }
}

__global__ void k_final(const float* __restrict__ x0, const float* __restrict__ h1,
                        const float* __restrict__ h2, const float* __restrict__ h3,
                        float* __restrict__ out) {
    int i = blockIdx.x * blockDim.x + threadIdx.x;
    if (i >= NN * DD) return;
    int r = i >> 6, lane = i & 63;
    out[(size_t)r * 256 + lane] = x0[i] + h1[i] + h2[i] + h3[i];
}

extern "C" void kernel_launch(void* const* d_in, const int* in_sizes, int n_in,
                              void* d_out, int out_size, void* d_ws, size_t ws_size,
                              hipStream_t stream) {
    const int* ei       = (const int*)d_in[0];
    const float* v_feat = (const float*)d_in[1];
    const float* a_feat = (const float*)d_in[2];
    const float* t_feat = (const float*)d_in[3];
    const float* pref_v = (const float*)d_in[4];
    const float* pref_a = (const float*)d_in[5];
    const float* pref_t = (const float*)d_in[6];
    const float* mlp_v_w = (const float*)d_in[7];
    const float* mlp_v_b = (const float*)d_in[8];
    const float* mlp_a_w = (const float*)d_in[9];
    const float* mlp_a_b = (const float*)d_in[10];
    const float* mlp_t_w = (const float*)d_in[11];
    const float* mlp_t_b = (const float*)d_in[12];
    const float* pre_w  = (const float*)d_in[13];
    const float* ori_w  = (const float*)d_in[14];
    const float* gcn_w  = (const float*)d_in[15];
    const float* id_emb = (const float*)d_in[16];
    float* out = (float*)d_out;

    const int E2 = in_sizes[0];   // total int elements = 2*E
    const int E  = E2 / 2;

    char* w = (char*)d_ws;
    auto alloc = [&](size_t bytes) -> void* {
        void* p = (void*)w;
        w += (bytes + 255) & ~(size_t)255;
        return p;
    };
    int* cnt = (int*)alloc((size_t)NN * 4);
    int* rp  = (int*)alloc((size_t)(NN + 1) * 4);
    int* col = (int*)alloc((size_t)E2 * 4);
    float* Mv = (float*)alloc((size_t)NN * DD * 4);
    float* Ma = (float*)alloc((size_t)NN * DD * 4);
    float* Mt = (float*)alloc((size_t)NN * DD * 4);
    float* xb = (float*)alloc((size_t)NN * DD * 4);
    float* hb = (float*)alloc((size_t)NN * DD * 4);
    float* gb = (float*)alloc((size_t)NN * DD * 4);
    float* Dv = (float*)alloc((size_t)E2 * 4);
    float* Da = (float*)alloc((size_t)E2 * 4);
    float* Dt = (float*)alloc((size_t)E2 * 4);

    // ---- CSR by destination ----
    hipMemsetAsync(cnt, 0, (size_t)NN * 4, stream);
    k_hist<<<(E2 + 255) / 256, 256, 0, stream>>>(ei, E2, E, cnt);
    k_scan<<<1, 1024, 0, stream>>>(cnt, rp, NN);
    hipMemsetAsync(cnt, 0, (size_t)NN * 4, stream);
    k_scatter<<<(E2 + 255) / 256, 256, 0, stream>>>(ei, E2, E, rp, cnt, col);

    // ---- per-modality node features ----
    k_l2rows<<<640, 256, 0, stream>>>(pref_v, Mv, NUSER);
    k_l2rows<<<640, 256, 0, stream>>>(pref_a, Ma, NUSER);
    k_l2rows<<<640, 256, 0, stream>>>(pref_t, Mt, NUSER);
    k_mlp<128><<<512, 256, 0, stream>>>(v_feat, mlp_v_w, mlp_v_b, Mv + (size_t)NUSER * DD, NITEM);
    k_mlp<128><<<512, 256, 0, stream>>>(a_feat, mlp_a_w, mlp_a_b, Ma + (size_t)NUSER * DD, NITEM);
    k_mlp<100><<<512, 256, 0, stream>>>(t_feat, mlp_t_w, mlp_t_b, Mt + (size_t)NUSER * DD, NITEM);

    const int GB = (NN + 3) / 4;  // one wave per node

    // ---- fixed-table edge dots for the cross-modal gates ----
    k_edgedot<<<GB, 256, 0, stream>>>(Mv, rp, col, Dv);
    k_edgedot<<<GB, 256, 0, stream>>>(Ma, rp, col, Da);
    k_edgedot<<<GB, 256, 0, stream>>>(Mt, rp, col, Dt);

    const float* Ms[3] = {Mv, Ma, Mt};
    const float* DYs[3] = {Da, Dv, Da};
    const float* DZs[3] = {Dt, Dt, Dv};
    const int coloff[3] = {64, 128, 192};

    for (int mo = 0; mo < 3; mo++) {
        k_gemm64<<<2500, 256, 0, stream>>>(Ms[mo], pre_w + (size_t)mo * 4096, hb, NN);
        k_gat_pre<<<GB, 256, 0, stream>>>(hb, DYs[mo], DZs[mo], rp, col, gb);
        k_l2rows<<<2500, 256, 0, stream>>>(gb, xb, NN);
        for (int it = 0; it < 3; it++) {
            k_gemm64<<<2500, 256, 0, stream>>>(xb, ori_w + (size_t)mo * 4096, hb, NN);
            k_gat_ori<<<GB, 256, 0, stream>>>(hb, rp, col, gb);
            if (it < 2)
                k_addl2<<<2500, 256, 0, stream>>>(xb, gb, xb, DD, NN);
            else
                k_addl2<<<2500, 256, 0, stream>>>(xb, gb, out + coloff[mo], 256, NN);
        }
    }

    // ---- real_gcn ----
    k_l2rows<<<2500, 256, 0, stream>>>(id_emb, Mv, NN);
    k_gemm64<<<2500, 256, 0, stream>>>(Mv, gcn_w + 0, hb, NN);
    k_gcn<<<GB, 256, 0, stream>>>(hb, rp, col, Ma, 1);
    k_gemm64<<<2500, 256, 0, stream>>>(Ma, gcn_w + 4096, hb, NN);
    k_gcn<<<GB, 256, 0, stream>>>(hb, rp, col, Mt, 1);
    k_gemm64<<<2500, 256, 0, stream>>>(Ma, gcn_w + 8192, hb, NN);
    k_gcn<<<GB, 256, 0, stream>>>(hb, rp, col, gb, 0);
    k_final<<<(NN * DD + 255) / 256, 256, 0, stream>>>(Mv, Ma, Mt, gb, out);
}

// Round 3
// 1168.857 us; speedup vs baseline: 2.1171x; 1.2394x over previous
//
#include <hip/hip_runtime.h>
#include <math.h>

#define NUSER 10000
#define NITEM 30000
#define NN    40000
#define DD    64
#define PLANE ((size_t)NN * DD)

struct P3 { float* a; float* b; float* c; };

__device__ __forceinline__ float wsum(float v) {
#pragma unroll
    for (int o = 32; o > 0; o >>= 1) v += __shfl_xor(v, o, 64);
    return v;
}
// reduce over the 16-lane dim-group (bits 0..3 of lane)
__device__ __forceinline__ float qsum16(float v) {
    v += __shfl_xor(v, 1, 64);
    v += __shfl_xor(v, 2, 64);
    v += __shfl_xor(v, 4, 64);
    v += __shfl_xor(v, 8, 64);
    return v;
}
// combine across the 4 edge-groups (bits 4,5)
__device__ __forceinline__ float gsum4(float v) {
    v += __shfl_xor(v, 16, 64);
    v += __shfl_xor(v, 32, 64);
    return v;
}

// ---------------- CSR build ----------------
__global__ void k_hist(const int* ei, int E2, int E, int* cnt) {
    int i = blockIdx.x * blockDim.x + threadIdx.x;
    if (i >= E2) return;
    int d = (i < E) ? ei[E + i] : ei[i - E];
    atomicAdd(&cnt[d], 1);
}

__global__ void k_bsum(const int* __restrict__ cnt, int* __restrict__ bsum, int n, int chunk) {
    __shared__ int wsh[4];
    int b = blockIdx.x, tid = threadIdx.x;
    int base = b * chunk, end = min(n, base + chunk);
    int s = 0;
    for (int i = base + tid; i < end; i += 256) s += cnt[i];
#pragma unroll
    for (int o = 32; o > 0; o >>= 1) s += __shfl_xor(s, o, 64);
    if ((tid & 63) == 0) wsh[tid >> 6] = s;
    __syncthreads();
    if (tid == 0) bsum[b] = wsh[0] + wsh[1] + wsh[2] + wsh[3];
}

__global__ void k_bscan(int* bsum, int nb, int* rp_end) {
    int lane = threadIdx.x;  // 64 threads
    int v = (lane < nb) ? bsum[lane] : 0;
    int orig = v;
#pragma unroll
    for (int o = 1; o < 64; o <<= 1) {
        int y = __shfl_up(v, o, 64);
        if (lane >= o) v += y;
    }
    if (lane < nb) bsum[lane] = v - orig;  // exclusive offsets
    if (lane == 63) *rp_end = v;           // total -> rp[NN]
}

__global__ void k_apply(const int* __restrict__ cnt, const int* __restrict__ boff,
                        int* __restrict__ rp, int n, int chunk) {
    __shared__ int buf[256];
    __shared__ int csh;
    int b = blockIdx.x, tid = threadIdx.x;
    int base = b * chunk, end = min(n, base + chunk);
    int carry = boff[b];
    for (int t0 = base; t0 < end; t0 += 256) {
        int i = t0 + tid;
        int v = (i < end) ? cnt[i] : 0;
        int x = v;
        buf[tid] = x;
        __syncthreads();
        for (int o = 1; o < 256; o <<= 1) {
            int y = (tid >= o) ? buf[tid - o] : 0;
            __syncthreads();
            x += y;
            buf[tid] = x;
            __syncthreads();
        }
        if (i < end) rp[i] = carry + x - v;
        __syncthreads();
        if (tid == 255) csh = carry + x;
        __syncthreads();
        carry = csh;
    }
}

__global__ void k_scatter(const int* ei, int E2, int E, const int* rp, int* fill, int* col) {
    int i = blockIdx.x * blockDim.x + threadIdx.x;
    if (i >= E2) return;
    int j = (i < E) ? i : i - E;
    int s = (i < E) ? ei[j] : ei[E + j];
    int d = (i < E) ? ei[E + j] : ei[j];
    int pos = rp[d] + atomicAdd(&fill[d], 1);
    col[pos] = s;
}

// ---------------- node prep ----------------
__global__ void k_l2rows(const float* __restrict__ in, float* __restrict__ out, int rows) {
    int t = blockIdx.x * blockDim.x + threadIdx.x;
    int w = t >> 6, lane = t & 63, nw = (gridDim.x * blockDim.x) >> 6;
    for (int r = w; r < rows; r += nw) {
        float v = in[(size_t)r * DD + lane];
        float n = sqrtf(wsum(v * v));
        out[(size_t)r * DD + lane] = v / fmaxf(n, 1e-12f);
    }
}

template <int K>
__global__ void k_mlp(const float* __restrict__ feat, const float* __restrict__ W,
                      const float* __restrict__ bias, float* __restrict__ out, int rows) {
    __shared__ float Wl[K][DD];
    __shared__ float rbuf[4][K];
    int t = threadIdx.x;
    for (int i = t; i < DD * K; i += 256) {
        int c = i / K, k = i - c * K;
        Wl[k][c] = W[i];
    }
    __syncthreads();
    int wib = t >> 6, lane = t & 63;
    float b = bias[lane];
    for (int r = blockIdx.x * 4 + wib; r < rows; r += gridDim.x * 4) {
        for (int k = lane; k < K; k += 64) rbuf[wib][k] = feat[(size_t)r * K + k];
        asm volatile("s_waitcnt lgkmcnt(0)" ::: "memory");
        float acc = b;
#pragma unroll 4
        for (int k = 0; k < K; k++) acc += rbuf[wib][k] * Wl[k][lane];
        float h = acc > 0.f ? acc : 0.01f * acc;
        float n = sqrtf(wsum(h * h));
        out[(size_t)r * DD + lane] = h / fmaxf(n, 1e-12f);
    }
}

// ---------------- 64x64 GEMM: out = x @ W (single plane) ----------------
__global__ void k_gemm64(const float* __restrict__ x, const float* __restrict__ W,
                         float* __restrict__ out, int rows) {
    __shared__ float Wl[DD][DD];
    __shared__ float rbuf[4][DD];
    int t = threadIdx.x;
    for (int i = t; i < DD * DD; i += 256) Wl[i >> 6][i & 63] = W[i];
    __syncthreads();
    int wib = t >> 6, lane = t & 63;
    for (int r = blockIdx.x * 4 + wib; r < rows; r += gridDim.x * 4) {
        rbuf[wib][lane] = x[(size_t)r * DD + lane];
        asm volatile("s_waitcnt lgkmcnt(0)" ::: "memory");
        float acc = 0.f;
#pragma unroll 8
        for (int k = 0; k < DD; k++) acc += rbuf[wib][k] * Wl[k][lane];
        out[(size_t)r * DD + lane] = acc;
    }
}

// batched over 3 planes: blockIdx.y = plane; W offset 4096 per plane
__global__ void k_gemm64b(const float* __restrict__ x3, const float* __restrict__ W3,
                          float* __restrict__ out3) {
    __shared__ float Wl[DD][DD];
    __shared__ float rbuf[4][DD];
    int mo = blockIdx.y;
    const float* x = x3 + (size_t)mo * PLANE;
    const float* W = W3 + (size_t)mo * 4096;
    float* out = out3 + (size_t)mo * PLANE;
    int t = threadIdx.x;
    for (int i = t; i < DD * DD; i += 256) Wl[i >> 6][i & 63] = W[i];
    __syncthreads();
    int wib = t >> 6, lane = t & 63;
    for (int r = blockIdx.x * 4 + wib; r < NN; r += gridDim.x * 4) {
        rbuf[wib][lane] = x[(size_t)r * DD + lane];
        asm volatile("s_waitcnt lgkmcnt(0)" ::: "memory");
        float acc = 0.f;
#pragma unroll 8
        for (int k = 0; k < DD; k++) acc += rbuf[wib][k] * Wl[k][lane];
        out[(size_t)r * DD + lane] = acc;
    }
}

// ---------------- fused 3-table edge dots ----------------
__global__ void k_edgedot3(const float* __restrict__ Mv, const float* __restrict__ Ma,
                           const float* __restrict__ Mt, const int* __restrict__ rp,
                           const int* __restrict__ col, float* __restrict__ Dv,
                           float* __restrict__ Da, float* __restrict__ Dt) {
    int t = blockIdx.x * blockDim.x + threadIdx.x;
    int w = t >> 6, lane = t & 63, nw = (gridDim.x * blockDim.x) >> 6;
    int g = lane >> 4, q = lane & 15;
    for (int n = w; n < NN; n += nw) {
        int e0 = rp[n], e1 = rp[n + 1];
        if (e0 == e1) continue;
        size_t db = (size_t)n * DD + q * 4;
        float4 tv = *(const float4*)(Mv + db);
        float4 ta = *(const float4*)(Ma + db);
        float4 tt = *(const float4*)(Mt + db);
        for (int eb = e0 + g; eb < e1; eb += 4) {
            int sn = col[eb];
            size_t sb = (size_t)sn * DD + q * 4;
            float4 sv = *(const float4*)(Mv + sb);
            float4 sa = *(const float4*)(Ma + sb);
            float4 st = *(const float4*)(Mt + sb);
            float dv = tv.x * sv.x + tv.y * sv.y + tv.z * sv.z + tv.w * sv.w;
            float da = ta.x * sa.x + ta.y * sa.y + ta.z * sa.z + ta.w * sa.w;
            float dt = tt.x * st.x + tt.y * st.y + tt.z * st.z + tt.w * st.w;
            dv = qsum16(dv);
            da = qsum16(da);
            dt = qsum16(dt);
            if (q == 0) {
                Dv[eb] = dv;
                Da[eb] = da;
                Dt[eb] = dt;
            }
        }
    }
}

// ---------------- GAT pre (batched, no-max softmax, fused l2norm out) ----------------
__global__ void k_gat_pre_b3(const float* __restrict__ h3, const float* __restrict__ Dv,
                             const float* __restrict__ Da, const float* __restrict__ Dt,
                             const int* __restrict__ rp, const int* __restrict__ col,
                             float* __restrict__ x3) {
    int mo = blockIdx.y;
    const float* h = h3 + (size_t)mo * PLANE;
    const float* Dy = (mo == 0) ? Da : (mo == 1) ? Dv : Da;
    const float* Dz = (mo == 2) ? Dv : Dt;
    float* op = x3 + (size_t)mo * PLANE;
    int t = blockIdx.x * blockDim.x + threadIdx.x;
    int w = t >> 6, lane = t & 63, nw = (gridDim.x * blockDim.x) >> 6;
    int g = lane >> 4, q = lane & 15;
    for (int n = w; n < NN; n += nw) {
        int e0 = rp[n], e1 = rp[n + 1];
        float4 hd = *(const float4*)(h + (size_t)n * DD + q * 4);
        float s = 0.f;
        float4 acc = make_float4(0.f, 0.f, 0.f, 0.f);
        for (int eb = e0 + g; eb < e1; eb += 4) {
            int sn = col[eb];
            float4 hs = *(const float4*)(h + (size_t)sn * DD + q * 4);
            float gy = Dy[eb], gz = Dz[eb];
            float d = hd.x * hs.x + hd.y * hs.y + hd.z * hs.z + hd.w * hs.w;
            d = qsum16(d);
            float sc = d > 0.f ? d : 0.2f * d;
            float p = __expf(sc);
            float gate = 1.f / (1.f + __expf(-0.5f * (gy + gz)));
            float gf = gate > 0.5f ? gate : 1.f;
            s += p;
            float pg = p * gf;
            acc.x += pg * hs.x;
            acc.y += pg * hs.y;
            acc.z += pg * hs.z;
            acc.w += pg * hs.w;
        }
        s = gsum4(s);
        acc.x = gsum4(acc.x);
        acc.y = gsum4(acc.y);
        acc.z = gsum4(acc.z);
        acc.w = gsum4(acc.w);
        float inv = 1.f / (s + 1e-16f);
        float4 o = make_float4(acc.x * inv, acc.y * inv, acc.z * inv, acc.w * inv);
        float nr = qsum16(o.x * o.x + o.y * o.y + o.z * o.z + o.w * o.w);
        float rinv = 1.f / fmaxf(sqrtf(nr), 1e-12f);
        if (g == 0) {
            *(float4*)(op + (size_t)n * DD + q * 4) =
                make_float4(o.x * rinv, o.y * rinv, o.z * rinv, o.w * rinv);
        }
    }
}

// ---------------- GAT ori (batched, no-max softmax, fused add+l2norm out) ----------------
__global__ void k_gat_ori_b3(const float* __restrict__ h3, const float* __restrict__ x3,
                             const int* __restrict__ rp, const int* __restrict__ col,
                             P3 outp, int ostride) {
    int mo = blockIdx.y;
    const float* h = h3 + (size_t)mo * PLANE;
    const float* x = x3 + (size_t)mo * PLANE;
    float* op = (mo == 0) ? outp.a : (mo == 1) ? outp.b : outp.c;
    int t = blockIdx.x * blockDim.x + threadIdx.x;
    int w = t >> 6, lane = t & 63, nw = (gridDim.x * blockDim.x) >> 6;
    int g = lane >> 4, q = lane & 15;
    for (int n = w; n < NN; n += nw) {
        int e0 = rp[n], e1 = rp[n + 1];
        float4 hd = *(const float4*)(h + (size_t)n * DD + q * 4);
        float s = 0.f;
        float4 acc = make_float4(0.f, 0.f, 0.f, 0.f);
        for (int eb = e0 + g; eb < e1; eb += 4) {
            int sn = col[eb];
            float4 hs = *(const float4*)(h + (size_t)sn * DD + q * 4);
            float d = hd.x * hs.x + hd.y * hs.y + hd.z * hs.z + hd.w * hs.w;
            d = qsum16(d);
            float sc = d > 0.f ? d : 0.2f * d;
            float p = __expf(sc);
            s += p;
            acc.x += p * hs.x;
            acc.y += p * hs.y;
            acc.z += p * hs.z;
            acc.w += p * hs.w;
        }
        s = gsum4(s);
        acc.x = gsum4(acc.x);
        acc.y = gsum4(acc.y);
        acc.z = gsum4(acc.z);
        acc.w = gsum4(acc.w);
        float inv = 1.f / (s + 1e-16f);
        float4 xr = *(const float4*)(x + (size_t)n * DD + q * 4);
        float4 o = make_float4(xr.x + acc.x * inv, xr.y + acc.y * inv,
                               xr.z + acc.z * inv, xr.w + acc.w * inv);
        float nr = qsum16(o.x * o.x + o.y * o.y + o.z * o.z + o.w * o.w);
        float rinv = 1.f / fmaxf(sqrtf(nr), 1e-12f);
        if (g == 0) {
            *(float4*)(op + (size_t)n * ostride + q * 4) =
                make_float4(o.x * rinv, o.y * rinv, o.z * rinv, o.w * rinv);
        }
    }
}

__global__ void k_gcn(const float* __restrict__ h, const int* __restrict__ rp,
                      const int* __restrict__ col, float* __restrict__ out, int leaky) {
    int t = blockIdx.x * blockDim.x + threadIdx.x;
    int w = t >> 6, lane = t & 63, nw = (gridDim.x * blockDim.x) >> 6;
    int g = lane >> 4, q = lane & 15;
    for (int n = w; n < NN; n += nw) {
        int e0 = rp[n], e1 = rp[n + 1];
        float4 acc = make_float4(0.f, 0.f, 0.f, 0.f);
        for (int eb = e0 + g; eb < e1; eb += 4) {
            int sn = col[eb];
            float4 hs = *(const float4*)(h + (size_t)sn * DD + q * 4);
            acc.x += hs.x;
            acc.y += hs.y;
            acc.z += hs.z;
            acc.w += hs.w;
        }
        acc.x = gsum4(acc.x);
        acc.y = gsum4(acc.y);
        acc.z = gsum4(acc.z);
        acc.w = gsum4(acc.w);
        if (leaky) {
            acc.x = acc.x > 0.f ? acc.x : 0.01f * acc.x;
            acc.y = acc.y > 0.f ? acc.y : 0.01f * acc.y;
            acc.z = acc.z > 0.f ? acc.z : 0.01f * acc.z;
            acc.w = acc.w > 0.f ? acc.w : 0.01f * acc.w;
        }
        if (g == 0) *(float4*)(out + (size_t)n * DD + q * 4) = acc;
    }
}

// final gcn layer fused with the 4-way sum: out[:, :64] = x0 + h1 + h2 + gcn(h)
__global__ void k_gcn_final(const float* __restrict__ h, const int* __restrict__ rp,
                            const int* __restrict__ col, const float* __restrict__ x0,
                            const float* __restrict__ h1, const float* __restrict__ h2,
                            float* __restrict__ out) {
    int t = blockIdx.x * blockDim.x + threadIdx.x;
    int w = t >> 6, lane = t & 63, nw = (gridDim.x * blockDim.x) >> 6;
    int g = lane >> 4, q = lane & 15;
    for (int n = w; n < NN; n += nw) {
        int e0 = rp[n], e1 = rp[n + 1];
        float4 acc = make_float4(0.f, 0.f, 0.f, 0.f);
        for (int eb = e0 + g; eb < e1; eb += 4) {
            int sn = col[eb];
            float4 hs = *(const float4*)(h + (size_t)sn * DD + q * 4);
            acc.x += hs.x;
            acc.y += hs.y;
            acc.z += hs.z;
            acc.w += hs.w;
        }
        acc.x = gsum4(acc.x);
        acc.y = gsum4(acc.y);
        acc.z = gsum4(acc.z);
        acc.w = gsum4(acc.w);
        if (g == 0) {
            size_t b = (size_t)n * DD + q * 4;
            float4 a0 = *(const float4*)(x0 + b);
            float4 a1 = *(const float4*)(h1 + b);
            float4 a2 = *(const float4*)(h2 + b);
            float4 o = make_float4(a0.x + a1.x + a2.x + acc.x, a0.y + a1.y + a2.y + acc.y,
                                   a0.z + a1.z + a2.z + acc.z, a0.w + a1.w + a2.w + acc.w);
            *(float4*)(out + (size_t)n * 256 + q * 4) = o;
        }
    }
}

extern "C" void kernel_launch(void* const* d_in, const int* in_sizes, int n_in,
                              void* d_out, int out_size, void* d_ws, size_t ws_size,
                              hipStream_t stream) {
    const int* ei       = (const int*)d_in[0];
    const float* v_feat = (const float*)d_in[1];
    const float* a_feat = (const float*)d_in[2];
    const float* t_feat = (const float*)d_in[3];
    const float* pref_v = (const float*)d_in[4];
    const float* pref_a = (const float*)d_in[5];
    const float* pref_t = (const float*)d_in[6];
    const float* mlp_v_w = (const float*)d_in[7];
    const float* mlp_v_b = (const float*)d_in[8];
    const float* mlp_a_w = (const float*)d_in[9];
    const float* mlp_a_b = (const float*)d_in[10];
    const float* mlp_t_w = (const float*)d_in[11];
    const float* mlp_t_b = (const float*)d_in[12];
    const float* pre_w  = (const float*)d_in[13];
    const float* ori_w  = (const float*)d_in[14];
    const float* gcn_w  = (const float*)d_in[15];
    const float* id_emb = (const float*)d_in[16];
    float* out = (float*)d_out;

    const int E2 = in_sizes[0];
    const int E  = E2 / 2;

    char* w = (char*)d_ws;
    auto alloc = [&](size_t bytes) -> void* {
        void* p = (void*)w;
        w += (bytes + 255) & ~(size_t)255;
        return p;
    };
    int* cnt  = (int*)alloc((size_t)NN * 4);
    int* rp   = (int*)alloc((size_t)(NN + 1) * 4);
    int* bsum = (int*)alloc(256);
    int* col  = (int*)alloc((size_t)E2 * 4);
    float* M3  = (float*)alloc(3 * PLANE * 4);
    float* xb3 = (float*)alloc(3 * PLANE * 4);
    float* hb3 = (float*)alloc(3 * PLANE * 4);
    float* Dv  = (float*)alloc((size_t)E2 * 4);
    float* Da  = (float*)alloc((size_t)E2 * 4);
    float* Dt  = (float*)alloc((size_t)E2 * 4);

    float* Mv = M3;
    float* Ma = M3 + PLANE;
    float* Mt = M3 + 2 * PLANE;

    // ---- CSR by destination (multi-block scan) ----
    const int NBLK = 64, CHUNK = (NN + NBLK - 1) / NBLK;
    hipMemsetAsync(cnt, 0, (size_t)NN * 4, stream);
    k_hist<<<(E2 + 255) / 256, 256, 0, stream>>>(ei, E2, E, cnt);
    k_bsum<<<NBLK, 256, 0, stream>>>(cnt, bsum, NN, CHUNK);
    k_bscan<<<1, 64, 0, stream>>>(bsum, NBLK, rp + NN);
    k_apply<<<NBLK, 256, 0, stream>>>(cnt, bsum, rp, NN, CHUNK);
    hipMemsetAsync(cnt, 0, (size_t)NN * 4, stream);
    k_scatter<<<(E2 + 255) / 256, 256, 0, stream>>>(ei, E2, E, rp, cnt, col);

    // ---- per-modality node tables ----
    k_l2rows<<<640, 256, 0, stream>>>(pref_v, Mv, NUSER);
    k_l2rows<<<640, 256, 0, stream>>>(pref_a, Ma, NUSER);
    k_l2rows<<<640, 256, 0, stream>>>(pref_t, Mt, NUSER);
    k_mlp<128><<<512, 256, 0, stream>>>(v_feat, mlp_v_w, mlp_v_b, Mv + (size_t)NUSER * DD, NITEM);
    k_mlp<128><<<512, 256, 0, stream>>>(a_feat, mlp_a_w, mlp_a_b, Ma + (size_t)NUSER * DD, NITEM);
    k_mlp<100><<<512, 256, 0, stream>>>(t_feat, mlp_t_w, mlp_t_b, Mt + (size_t)NUSER * DD, NITEM);

    const int GB = (NN + 3) / 4;  // one wave per node

    // ---- fused cross-modal gate dots ----
    k_edgedot3<<<GB, 256, 0, stream>>>(Mv, Ma, Mt, rp, col, Dv, Da, Dt);

    // ---- 3-modality chains, batched over blockIdx.y ----
    dim3 gemmg(2500, 3), gatg(GB, 3);
    k_gemm64b<<<gemmg, 256, 0, stream>>>(M3, pre_w, hb3);
    k_gat_pre_b3<<<gatg, 256, 0, stream>>>(hb3, Dv, Da, Dt, rp, col, xb3);
    for (int it = 0; it < 3; it++) {
        k_gemm64b<<<gemmg, 256, 0, stream>>>(xb3, ori_w, hb3);
        P3 outp;
        int ostride;
        if (it < 2) {
            outp = {xb3, xb3 + PLANE, xb3 + 2 * PLANE};
            ostride = DD;
        } else {
            outp = {out + 64, out + 128, out + 192};
            ostride = 256;
        }
        k_gat_ori_b3<<<gatg, 256, 0, stream>>>(hb3, xb3, rp, col, outp, ostride);
    }

    // ---- real_gcn: x0 = M3 plane0, h1 = plane1, h2 = plane2 ----
    float* x0 = M3;
    float* h1 = M3 + PLANE;
    float* h2 = M3 + 2 * PLANE;
    k_l2rows<<<2500, 256, 0, stream>>>(id_emb, x0, NN);
    k_gemm64<<<2500, 256, 0, stream>>>(x0, gcn_w + 0, hb3, NN);
    k_gcn<<<GB, 256, 0, stream>>>(hb3, rp, col, h1, 1);
    k_gemm64<<<2500, 256, 0, stream>>>(h1, gcn_w + 4096, hb3, NN);
    k_gcn<<<GB, 256, 0, stream>>>(hb3, rp, col, h2, 1);
    k_gemm64<<<2500, 256, 0, stream>>>(h1, gcn_w + 8192, hb3, NN);
    k_gcn_final<<<GB, 256, 0, stream>>>(hb3, rp, col, x0, h1, h2, out);
}

// Round 4
// 1061.300 us; speedup vs baseline: 2.3316x; 1.1013x over previous
//
#include <hip/hip_runtime.h>
#include <hip/hip_fp16.h>
#include <math.h>

#define NUSER 10000
#define NITEM 30000
#define NN    40000
#define DD    64
#define PLANE ((size_t)NN * DD)

struct P3 { float* a; float* b; float* c; };

union HU2 { unsigned u; __half2 h; };

__device__ __forceinline__ float4 h4_to_f4(uint2 v) {
    HU2 a, b;
    a.u = v.x;
    b.u = v.y;
    float2 fa = __half22float2(a.h), fb = __half22float2(b.h);
    return make_float4(fa.x, fa.y, fb.x, fb.y);
}

__device__ __forceinline__ float wsum(float v) {
#pragma unroll
    for (int o = 32; o > 0; o >>= 1) v += __shfl_xor(v, o, 64);
    return v;
}
__device__ __forceinline__ float qsum16(float v) {
    v += __shfl_xor(v, 1, 64);
    v += __shfl_xor(v, 2, 64);
    v += __shfl_xor(v, 4, 64);
    v += __shfl_xor(v, 8, 64);
    return v;
}
__device__ __forceinline__ float gsum4(float v) {
    v += __shfl_xor(v, 16, 64);
    v += __shfl_xor(v, 32, 64);
    return v;
}

// ---------------- CSR build ----------------
__global__ void k_hist(const int* ei, int E2, int E, int* cnt) {
    int i = blockIdx.x * blockDim.x + threadIdx.x;
    if (i >= E2) return;
    int d = (i < E) ? ei[E + i] : ei[i - E];
    atomicAdd(&cnt[d], 1);
}

__global__ void k_bsum(const int* __restrict__ cnt, int* __restrict__ bsum, int n, int chunk) {
    __shared__ int wsh[4];
    int b = blockIdx.x, tid = threadIdx.x;
    int base = b * chunk, end = min(n, base + chunk);
    int s = 0;
    for (int i = base + tid; i < end; i += 256) s += cnt[i];
#pragma unroll
    for (int o = 32; o > 0; o >>= 1) s += __shfl_xor(s, o, 64);
    if ((tid & 63) == 0) wsh[tid >> 6] = s;
    __syncthreads();
    if (tid == 0) bsum[b] = wsh[0] + wsh[1] + wsh[2] + wsh[3];
}

__global__ void k_bscan(int* bsum, int nb, int* rp_end) {
    int lane = threadIdx.x;
    int v = (lane < nb) ? bsum[lane] : 0;
    int orig = v;
#pragma unroll
    for (int o = 1; o < 64; o <<= 1) {
        int y = __shfl_up(v, o, 64);
        if (lane >= o) v += y;
    }
    if (lane < nb) bsum[lane] = v - orig;
    if (lane == 63) *rp_end = v;
}

__global__ void k_apply(const int* __restrict__ cnt, const int* __restrict__ boff,
                        int* __restrict__ rp, int n, int chunk) {
    __shared__ int buf[256];
    __shared__ int csh;
    int b = blockIdx.x, tid = threadIdx.x;
    int base = b * chunk, end = min(n, base + chunk);
    int carry = boff[b];
    for (int t0 = base; t0 < end; t0 += 256) {
        int i = t0 + tid;
        int v = (i < end) ? cnt[i] : 0;
        int x = v;
        buf[tid] = x;
        __syncthreads();
        for (int o = 1; o < 256; o <<= 1) {
            int y = (tid >= o) ? buf[tid - o] : 0;
            __syncthreads();
            x += y;
            buf[tid] = x;
            __syncthreads();
        }
        if (i < end) rp[i] = carry + x - v;
        __syncthreads();
        if (tid == 255) csh = carry + x;
        __syncthreads();
        carry = csh;
    }
}

__global__ void k_scatter(const int* ei, int E2, int E, const int* rp, int* fill, int* col) {
    int i = blockIdx.x * blockDim.x + threadIdx.x;
    if (i >= E2) return;
    int j = (i < E) ? i : i - E;
    int s = (i < E) ? ei[j] : ei[E + j];
    int d = (i < E) ? ei[E + j] : ei[j];
    int pos = rp[d] + atomicAdd(&fill[d], 1);
    col[pos] = s;
}

// ---------------- node prep ----------------
__global__ void k_l2rows(const float* __restrict__ in, float* __restrict__ out, int rows) {
    int t = blockIdx.x * blockDim.x + threadIdx.x;
    int w = t >> 6, lane = t & 63, nw = (gridDim.x * blockDim.x) >> 6;
    for (int r = w; r < rows; r += nw) {
        float v = in[(size_t)r * DD + lane];
        float n = sqrtf(wsum(v * v));
        out[(size_t)r * DD + lane] = v / fmaxf(n, 1e-12f);
    }
}

// MLP: out = l2norm(leaky(feat @ W.T + b)); W is [DD][K]; per-lane W row in VGPRs
template <int K>
__global__ void k_mlp(const float* __restrict__ feat, const float* __restrict__ W,
                      const float* __restrict__ bias, float* __restrict__ out, int rows) {
    __shared__ float rbuf[4][K];
    int t = threadIdx.x, wib = t >> 6, lane = t & 63;
    float Wr[K];
#pragma unroll
    for (int k4 = 0; k4 < K / 4; k4++) {
        float4 w4 = *(const float4*)(W + (size_t)lane * K + k4 * 4);
        Wr[k4 * 4 + 0] = w4.x;
        Wr[k4 * 4 + 1] = w4.y;
        Wr[k4 * 4 + 2] = w4.z;
        Wr[k4 * 4 + 3] = w4.w;
    }
    float b = bias[lane];
    for (int r = blockIdx.x * 4 + wib; r < rows; r += gridDim.x * 4) {
        for (int k = lane; k < K; k += 64) rbuf[wib][k] = feat[(size_t)r * K + k];
        asm volatile("s_waitcnt lgkmcnt(0)" ::: "memory");
        float acc = b;
#pragma unroll
        for (int k4 = 0; k4 < K / 4; k4++) {
            float4 xq = *(const float4*)&rbuf[wib][k4 * 4];
            acc += xq.x * Wr[k4 * 4] + xq.y * Wr[k4 * 4 + 1] + xq.z * Wr[k4 * 4 + 2] +
                   xq.w * Wr[k4 * 4 + 3];
        }
        float h = acc > 0.f ? acc : 0.01f * acc;
        float n = sqrtf(wsum(h * h));
        out[(size_t)r * DD + lane] = h / fmaxf(n, 1e-12f);
    }
}

// ---------------- 64x64 GEMM, fp32 in, fp16 out; W column in VGPRs ----------------
// optional: l2-normalize input row first (do_l2), write normalized row to xnorm
__global__ void k_gemm64h(const float* __restrict__ x, const float* __restrict__ W,
                          __half* __restrict__ hout, float* __restrict__ xnorm, int rows,
                          int do_l2) {
    __shared__ float rowbuf[4][DD];
    int t = threadIdx.x, wib = t >> 6, lane = t & 63;
    float Wc[DD];
#pragma unroll
    for (int k = 0; k < DD; k++) Wc[k] = W[k * DD + lane];
    for (int r = blockIdx.x * 4 + wib; r < rows; r += gridDim.x * 4) {
        float xv = x[(size_t)r * DD + lane];
        if (do_l2) {
            float n = sqrtf(wsum(xv * xv));
            xv /= fmaxf(n, 1e-12f);
            if (xnorm) xnorm[(size_t)r * DD + lane] = xv;
        }
        rowbuf[wib][lane] = xv;
        asm volatile("s_waitcnt lgkmcnt(0)" ::: "memory");
        float acc = 0.f;
#pragma unroll
        for (int k4 = 0; k4 < DD / 4; k4++) {
            float4 xq = *(const float4*)&rowbuf[wib][k4 * 4];
            acc += xq.x * Wc[k4 * 4] + xq.y * Wc[k4 * 4 + 1] + xq.z * Wc[k4 * 4 + 2] +
                   xq.w * Wc[k4 * 4 + 3];
        }
        hout[(size_t)r * DD + lane] = __float2half(acc);
    }
}

// batched over 3 planes
__global__ void k_gemm64bh(const float* __restrict__ x3, const float* __restrict__ W3,
                           __half* __restrict__ out3) {
    __shared__ float rowbuf[4][DD];
    int mo = blockIdx.y;
    const float* x = x3 + (size_t)mo * PLANE;
    const float* W = W3 + (size_t)mo * 4096;
    __half* out = out3 + (size_t)mo * PLANE;
    int t = threadIdx.x, wib = t >> 6, lane = t & 63;
    float Wc[DD];
#pragma unroll
    for (int k = 0; k < DD; k++) Wc[k] = W[k * DD + lane];
    for (int r = blockIdx.x * 4 + wib; r < NN; r += gridDim.x * 4) {
        rowbuf[wib][lane] = x[(size_t)r * DD + lane];
        asm volatile("s_waitcnt lgkmcnt(0)" ::: "memory");
        float acc = 0.f;
#pragma unroll
        for (int k4 = 0; k4 < DD / 4; k4++) {
            float4 xq = *(const float4*)&rowbuf[wib][k4 * 4];
            acc += xq.x * Wc[k4 * 4] + xq.y * Wc[k4 * 4 + 1] + xq.z * Wc[k4 * 4 + 2] +
                   xq.w * Wc[k4 * 4 + 3];
        }
        out[(size_t)r * DD + lane] = __float2half(acc);
    }
}

// ---------------- fused 3-table edge dots + per-modality gates (fp32 tables) ----------------
__device__ __forceinline__ float gatef(float ssum) {
    float gate = 1.f / (1.f + __expf(-0.5f * ssum));
    return gate > 0.5f ? gate : 1.f;
}

__global__ void k_edgedot3(const float* __restrict__ Mv, const float* __restrict__ Ma,
                           const float* __restrict__ Mt, const int* __restrict__ rp,
                           const int* __restrict__ col, __half* __restrict__ gf3, int E2) {
    int t = blockIdx.x * blockDim.x + threadIdx.x;
    int w = t >> 6, lane = t & 63, nw = (gridDim.x * blockDim.x) >> 6;
    int g = lane >> 4, q = lane & 15;
    for (int n = w; n < NN; n += nw) {
        int e0 = rp[n], e1 = rp[n + 1];
        if (e0 == e1) continue;
        size_t db = (size_t)n * DD + q * 4;
        float4 tv = *(const float4*)(Mv + db);
        float4 ta = *(const float4*)(Ma + db);
        float4 tt = *(const float4*)(Mt + db);
        for (int eb = e0 + g; eb < e1; eb += 4) {
            int sn = col[eb];
            size_t sb = (size_t)sn * DD + q * 4;
            float4 sv = *(const float4*)(Mv + sb);
            float4 sa = *(const float4*)(Ma + sb);
            float4 st = *(const float4*)(Mt + sb);
            float dv = tv.x * sv.x + tv.y * sv.y + tv.z * sv.z + tv.w * sv.w;
            float da = ta.x * sa.x + ta.y * sa.y + ta.z * sa.z + ta.w * sa.w;
            float dt = tt.x * st.x + tt.y * st.y + tt.z * st.z + tt.w * st.w;
            dv = qsum16(dv);
            da = qsum16(da);
            dt = qsum16(dt);
            if (q == 0) {
                gf3[eb] = __float2half(gatef(da + dt));               // mo 0: (a,t)
                gf3[(size_t)E2 + eb] = __float2half(gatef(dv + dt));  // mo 1: (v,t)
                gf3[(size_t)2 * E2 + eb] = __float2half(gatef(da + dv));  // mo 2: (a,v)
            }
        }
    }
}

// ---------------- GAT pre (fp16 gathers, precomputed gate, fused l2norm) ----------------
__global__ void k_gat_pre_b3(const __half* __restrict__ h3, const __half* __restrict__ gf3,
                             const int* __restrict__ rp, const int* __restrict__ col,
                             float* __restrict__ x3, int E2) {
    int mo = blockIdx.y;
    const __half* h = h3 + (size_t)mo * PLANE;
    const __half* gf = gf3 + (size_t)mo * E2;
    float* op = x3 + (size_t)mo * PLANE;
    int t = blockIdx.x * blockDim.x + threadIdx.x;
    int w = t >> 6, lane = t & 63, nw = (gridDim.x * blockDim.x) >> 6;
    int g = lane >> 4, q = lane & 15;
    for (int n = w; n < NN; n += nw) {
        int e0 = rp[n], e1 = rp[n + 1];
        float4 hd = h4_to_f4(*(const uint2*)(h + (size_t)n * DD + q * 4));
        float s = 0.f;
        float4 acc = make_float4(0.f, 0.f, 0.f, 0.f);
        for (int eb = e0 + g; eb < e1; eb += 4) {
            int sn = col[eb];
            float4 hs = h4_to_f4(*(const uint2*)(h + (size_t)sn * DD + q * 4));
            float gv = __half2float(gf[eb]);
            float d = hd.x * hs.x + hd.y * hs.y + hd.z * hs.z + hd.w * hs.w;
            d = qsum16(d);
            float sc = d > 0.f ? d : 0.2f * d;
            float p = __expf(sc);
            s += p;
            float pg = p * gv;
            acc.x += pg * hs.x;
            acc.y += pg * hs.y;
            acc.z += pg * hs.z;
            acc.w += pg * hs.w;
        }
        s = gsum4(s);
        acc.x = gsum4(acc.x);
        acc.y = gsum4(acc.y);
        acc.z = gsum4(acc.z);
        acc.w = gsum4(acc.w);
        float inv = 1.f / (s + 1e-16f);
        float4 o = make_float4(acc.x * inv, acc.y * inv, acc.z * inv, acc.w * inv);
        float nr = qsum16(o.x * o.x + o.y * o.y + o.z * o.z + o.w * o.w);
        float rinv = 1.f / fmaxf(sqrtf(nr), 1e-12f);
        if (g == 0) {
            *(float4*)(op + (size_t)n * DD + q * 4) =
                make_float4(o.x * rinv, o.y * rinv, o.z * rinv, o.w * rinv);
        }
    }
}

// ---------------- GAT ori (fp16 gathers, fused residual+l2norm) ----------------
__global__ void k_gat_ori_b3(const __half* __restrict__ h3, const float* __restrict__ x3,
                             const int* __restrict__ rp, const int* __restrict__ col, P3 outp,
                             int ostride) {
    int mo = blockIdx.y;
    const __half* h = h3 + (size_t)mo * PLANE;
    const float* x = x3 + (size_t)mo * PLANE;
    float* op = (mo == 0) ? outp.a : (mo == 1) ? outp.b : outp.c;
    int t = blockIdx.x * blockDim.x + threadIdx.x;
    int w = t >> 6, lane = t & 63, nw = (gridDim.x * blockDim.x) >> 6;
    int g = lane >> 4, q = lane & 15;
    for (int n = w; n < NN; n += nw) {
        int e0 = rp[n], e1 = rp[n + 1];
        float4 hd = h4_to_f4(*(const uint2*)(h + (size_t)n * DD + q * 4));
        float s = 0.f;
        float4 acc = make_float4(0.f, 0.f, 0.f, 0.f);
        for (int eb = e0 + g; eb < e1; eb += 4) {
            int sn = col[eb];
            float4 hs = h4_to_f4(*(const uint2*)(h + (size_t)sn * DD + q * 4));
            float d = hd.x * hs.x + hd.y * hs.y + hd.z * hs.z + hd.w * hs.w;
            d = qsum16(d);
            float sc = d > 0.f ? d : 0.2f * d;
            float p = __expf(sc);
            s += p;
            acc.x += p * hs.x;
            acc.y += p * hs.y;
            acc.z += p * hs.z;
            acc.w += p * hs.w;
        }
        s = gsum4(s);
        acc.x = gsum4(acc.x);
        acc.y = gsum4(acc.y);
        acc.z = gsum4(acc.z);
        acc.w = gsum4(acc.w);
        float inv = 1.f / (s + 1e-16f);
        float4 xr = *(const float4*)(x + (size_t)n * DD + q * 4);
        float4 o = make_float4(xr.x + acc.x * inv, xr.y + acc.y * inv, xr.z + acc.z * inv,
                               xr.w + acc.w * inv);
        float nr = qsum16(o.x * o.x + o.y * o.y + o.z * o.z + o.w * o.w);
        float rinv = 1.f / fmaxf(sqrtf(nr), 1e-12f);
        if (g == 0) {
            *(float4*)(op + (size_t)n * ostride + q * 4) =
                make_float4(o.x * rinv, o.y * rinv, o.z * rinv, o.w * rinv);
        }
    }
}

__global__ void k_gcn(const __half* __restrict__ h, const int* __restrict__ rp,
                      const int* __restrict__ col, float* __restrict__ out, int leaky) {
    int t = blockIdx.x * blockDim.x + threadIdx.x;
    int w = t >> 6, lane = t & 63, nw = (gridDim.x * blockDim.x) >> 6;
    int g = lane >> 4, q = lane & 15;
    for (int n = w; n < NN; n += nw) {
        int e0 = rp[n], e1 = rp[n + 1];
        float4 acc = make_float4(0.f, 0.f, 0.f, 0.f);
        for (int eb = e0 + g; eb < e1; eb += 4) {
            int sn = col[eb];
            float4 hs = h4_to_f4(*(const uint2*)(h + (size_t)sn * DD + q * 4));
            acc.x += hs.x;
            acc.y += hs.y;
            acc.z += hs.z;
            acc.w += hs.w;
        }
        acc.x = gsum4(acc.x);
        acc.y = gsum4(acc.y);
        acc.z = gsum4(acc.z);
        acc.w = gsum4(acc.w);
        if (leaky) {
            acc.x = acc.x > 0.f ? acc.x : 0.01f * acc.x;
            acc.y = acc.y > 0.f ? acc.y : 0.01f * acc.y;
            acc.z = acc.z > 0.f ? acc.z : 0.01f * acc.z;
            acc.w = acc.w > 0.f ? acc.w : 0.01f * acc.w;
        }
        if (g == 0) *(float4*)(out + (size_t)n * DD + q * 4) = acc;
    }
}

__global__ void k_gcn_final(const __half* __restrict__ h, const int* __restrict__ rp,
                            const int* __restrict__ col, const float* __restrict__ x0,
                            const float* __restrict__ h1, const float* __restrict__ h2,
                            float* __restrict__ out) {
    int t = blockIdx.x * blockDim.x + threadIdx.x;
    int w = t >> 6, lane = t & 63, nw = (gridDim.x * blockDim.x) >> 6;
    int g = lane >> 4, q = lane & 15;
    for (int n = w; n < NN; n += nw) {
        int e0 = rp[n], e1 = rp[n + 1];
        float4 acc = make_float4(0.f, 0.f, 0.f, 0.f);
        for (int eb = e0 + g; eb < e1; eb += 4) {
            int sn = col[eb];
            float4 hs = h4_to_f4(*(const uint2*)(h + (size_t)sn * DD + q * 4));
            acc.x += hs.x;
            acc.y += hs.y;
            acc.z += hs.z;
            acc.w += hs.w;
        }
        acc.x = gsum4(acc.x);
        acc.y = gsum4(acc.y);
        acc.z = gsum4(acc.z);
        acc.w = gsum4(acc.w);
        if (g == 0) {
            size_t b = (size_t)n * DD + q * 4;
            float4 a0 = *(const float4*)(x0 + b);
            float4 a1 = *(const float4*)(h1 + b);
            float4 a2 = *(const float4*)(h2 + b);
            float4 o = make_float4(a0.x + a1.x + a2.x + acc.x, a0.y + a1.y + a2.y + acc.y,
                                   a0.z + a1.z + a2.z + acc.z, a0.w + a1.w + a2.w + acc.w);
            *(float4*)(out + (size_t)n * 256 + q * 4) = o;
        }
    }
}

extern "C" void kernel_launch(void* const* d_in, const int* in_sizes, int n_in,
                              void* d_out, int out_size, void* d_ws, size_t ws_size,
                              hipStream_t stream) {
    const int* ei       = (const int*)d_in[0];
    const float* v_feat = (const float*)d_in[1];
    const float* a_feat = (const float*)d_in[2];
    const float* t_feat = (const float*)d_in[3];
    const float* pref_v = (const float*)d_in[4];
    const float* pref_a = (const float*)d_in[5];
    const float* pref_t = (const float*)d_in[6];
    const float* mlp_v_w = (const float*)d_in[7];
    const float* mlp_v_b = (const float*)d_in[8];
    const float* mlp_a_w = (const float*)d_in[9];
    const float* mlp_a_b = (const float*)d_in[10];
    const float* mlp_t_w = (const float*)d_in[11];
    const float* mlp_t_b = (const float*)d_in[12];
    const float* pre_w  = (const float*)d_in[13];
    const float* ori_w  = (const float*)d_in[14];
    const float* gcn_w  = (const float*)d_in[15];
    const float* id_emb = (const float*)d_in[16];
    float* out = (float*)d_out;

    const int E2 = in_sizes[0];
    const int E  = E2 / 2;

    char* w = (char*)d_ws;
    auto alloc = [&](size_t bytes) -> void* {
        void* p = (void*)w;
        w += (bytes + 255) & ~(size_t)255;
        return p;
    };
    int* cnt  = (int*)alloc((size_t)NN * 4);
    int* rp   = (int*)alloc((size_t)(NN + 1) * 4);
    int* bsum = (int*)alloc(256);
    int* col  = (int*)alloc((size_t)E2 * 4);
    float* M3   = (float*)alloc(3 * PLANE * 4);
    float* x3   = (float*)alloc(3 * PLANE * 4);
    __half* hb3h = (__half*)alloc(3 * PLANE * 2);
    __half* gf3  = (__half*)alloc((size_t)3 * E2 * 2);

    float* Mv = M3;
    float* Ma = M3 + PLANE;
    float* Mt = M3 + 2 * PLANE;

    // ---- CSR by destination ----
    const int NBLK = 64, CHUNK = (NN + NBLK - 1) / NBLK;
    hipMemsetAsync(cnt, 0, (size_t)NN * 4, stream);
    k_hist<<<(E2 + 255) / 256, 256, 0, stream>>>(ei, E2, E, cnt);
    k_bsum<<<NBLK, 256, 0, stream>>>(cnt, bsum, NN, CHUNK);
    k_bscan<<<1, 64, 0, stream>>>(bsum, NBLK, rp + NN);
    k_apply<<<NBLK, 256, 0, stream>>>(cnt, bsum, rp, NN, CHUNK);
    hipMemsetAsync(cnt, 0, (size_t)NN * 4, stream);
    k_scatter<<<(E2 + 255) / 256, 256, 0, stream>>>(ei, E2, E, rp, cnt, col);

    // ---- per-modality node tables (fp32 M3) ----
    k_l2rows<<<640, 256, 0, stream>>>(pref_v, Mv, NUSER);
    k_l2rows<<<640, 256, 0, stream>>>(pref_a, Ma, NUSER);
    k_l2rows<<<640, 256, 0, stream>>>(pref_t, Mt, NUSER);
    k_mlp<128><<<512, 256, 0, stream>>>(v_feat, mlp_v_w, mlp_v_b, Mv + (size_t)NUSER * DD, NITEM);
    k_mlp<128><<<512, 256, 0, stream>>>(a_feat, mlp_a_w, mlp_a_b, Ma + (size_t)NUSER * DD, NITEM);
    k_mlp<100><<<512, 256, 0, stream>>>(t_feat, mlp_t_w, mlp_t_b, Mt + (size_t)NUSER * DD, NITEM);

    const int GB = (NN + 3) / 4;

    // ---- cross-modal gate factors (fp32 dots, fp16 gates) ----
    k_edgedot3<<<GB, 256, 0, stream>>>(Mv, Ma, Mt, rp, col, gf3, E2);

    // ---- 3-modality chains ----
    dim3 gemmg(1280, 3), gatg(GB, 3);
    k_gemm64bh<<<gemmg, 256, 0, stream>>>(M3, pre_w, hb3h);
    k_gat_pre_b3<<<gatg, 256, 0, stream>>>(hb3h, gf3, rp, col, x3, E2);
    for (int it = 0; it < 3; it++) {
        k_gemm64bh<<<gemmg, 256, 0, stream>>>(x3, ori_w, hb3h);
        P3 outp;
        int ostride;
        if (it < 2) {
            outp = {x3, x3 + PLANE, x3 + 2 * PLANE};
            ostride = DD;
        } else {
            outp = {out + 64, out + 128, out + 192};
            ostride = 256;
        }
        k_gat_ori_b3<<<gatg, 256, 0, stream>>>(hb3h, x3, rp, col, outp, ostride);
    }

    // ---- real_gcn: x0/h1/h2 reuse M3 planes; hb3h reused as fp16 h ----
    float* x0 = M3;
    float* h1 = M3 + PLANE;
    float* h2 = M3 + 2 * PLANE;
    k_gemm64h<<<1280, 256, 0, stream>>>(id_emb, gcn_w + 0, hb3h, x0, NN, 1);
    k_gcn<<<GB, 256, 0, stream>>>(hb3h, rp, col, h1, 1);
    k_gemm64h<<<1280, 256, 0, stream>>>(h1, gcn_w + 4096, hb3h, nullptr, NN, 0);
    k_gcn<<<GB, 256, 0, stream>>>(hb3h, rp, col, h2, 1);
    k_gemm64h<<<1280, 256, 0, stream>>>(h1, gcn_w + 8192, hb3h, nullptr, NN, 0);
    k_gcn_final<<<GB, 256, 0, stream>>>(hb3h, rp, col, x0, h1, h2, out);
}

// Round 5
// 827.639 us; speedup vs baseline: 2.9899x; 1.2823x over previous
//
#include <hip/hip_runtime.h>
#include <hip/hip_fp16.h>
#include <math.h>

#define NUSER 10000
#define NITEM 30000
#define NN    40000
#define DD    64
#define PLANE ((size_t)NN * DD)

union HU { unsigned u; __half2 h; };

__device__ __forceinline__ float4 h4_to_f4(uint2 v) {
    HU a, b;
    a.u = v.x;
    b.u = v.y;
    float2 fa = __half22float2(a.h), fb = __half22float2(b.h);
    return make_float4(fa.x, fa.y, fb.x, fb.y);
}

__device__ __forceinline__ float wsum(float v) {
#pragma unroll
    for (int o = 32; o > 0; o >>= 1) v += __shfl_xor(v, o, 64);
    return v;
}
__device__ __forceinline__ float qsum16(float v) {
    v += __shfl_xor(v, 1, 64);
    v += __shfl_xor(v, 2, 64);
    v += __shfl_xor(v, 4, 64);
    v += __shfl_xor(v, 8, 64);
    return v;
}
__device__ __forceinline__ float gsum4(float v) {
    v += __shfl_xor(v, 16, 64);
    v += __shfl_xor(v, 32, 64);
    return v;
}
__device__ __forceinline__ float dot4(float4 a, float4 b) {
    return a.x * b.x + a.y * b.y + a.z * b.z + a.w * b.w;
}

// ---------------- CSR build ----------------
__global__ void k_hist(const int* ei, int E2, int E, int* cnt) {
    int i = blockIdx.x * blockDim.x + threadIdx.x;
    if (i >= E2) return;
    int d = (i < E) ? ei[E + i] : ei[i - E];
    atomicAdd(&cnt[d], 1);
}

__global__ void k_bsum(const int* __restrict__ cnt, int* __restrict__ bsum, int n, int chunk) {
    __shared__ int wsh[4];
    int b = blockIdx.x, tid = threadIdx.x;
    int base = b * chunk, end = min(n, base + chunk);
    int s = 0;
    for (int i = base + tid; i < end; i += 256) s += cnt[i];
#pragma unroll
    for (int o = 32; o > 0; o >>= 1) s += __shfl_xor(s, o, 64);
    if ((tid & 63) == 0) wsh[tid >> 6] = s;
    __syncthreads();
    if (tid == 0) bsum[b] = wsh[0] + wsh[1] + wsh[2] + wsh[3];
}

__global__ void k_bscan(int* bsum, int nb, int* rp_end) {
    int lane = threadIdx.x;
    int v = (lane < nb) ? bsum[lane] : 0;
    int orig = v;
#pragma unroll
    for (int o = 1; o < 64; o <<= 1) {
        int y = __shfl_up(v, o, 64);
        if (lane >= o) v += y;
    }
    if (lane < nb) bsum[lane] = v - orig;
    if (lane == 63) *rp_end = v;
}

__global__ void k_apply(const int* __restrict__ cnt, const int* __restrict__ boff,
                        int* __restrict__ rp, int n, int chunk) {
    __shared__ int buf[256];
    __shared__ int csh;
    int b = blockIdx.x, tid = threadIdx.x;
    int base = b * chunk, end = min(n, base + chunk);
    int carry = boff[b];
    for (int t0 = base; t0 < end; t0 += 256) {
        int i = t0 + tid;
        int v = (i < end) ? cnt[i] : 0;
        int x = v;
        buf[tid] = x;
        __syncthreads();
        for (int o = 1; o < 256; o <<= 1) {
            int y = (tid >= o) ? buf[tid - o] : 0;
            __syncthreads();
            x += y;
            buf[tid] = x;
            __syncthreads();
        }
        if (i < end) rp[i] = carry + x - v;
        __syncthreads();
        if (tid == 255) csh = carry + x;
        __syncthreads();
        carry = csh;
    }
}

__global__ void k_scatter(const int* ei, int E2, int E, const int* rp, int* fill, int* col) {
    int i = blockIdx.x * blockDim.x + threadIdx.x;
    if (i >= E2) return;
    int j = (i < E) ? i : i - E;
    int s = (i < E) ? ei[j] : ei[E + j];
    int d = (i < E) ? ei[E + j] : ei[j];
    int pos = rp[d] + atomicAdd(&fill[d], 1);
    col[pos] = s;
}

// ---------------- node prep: 3 prefs -> interleaved fp16 M ----------------
__global__ void k_prep_pref(const float* __restrict__ pv, const float* __restrict__ pa,
                            const float* __restrict__ pt, __half* __restrict__ M) {
    int t = blockIdx.x * blockDim.x + threadIdx.x;
    int w = t >> 6, lane = t & 63, nw = (gridDim.x * blockDim.x) >> 6;
    for (int r = w; r < NUSER; r += nw) {
        float a = pv[(size_t)r * DD + lane];
        float b = pa[(size_t)r * DD + lane];
        float c = pt[(size_t)r * DD + lane];
        float sa = a * a, sb = b * b, sc = c * c;
#pragma unroll
        for (int o = 32; o > 0; o >>= 1) {
            sa += __shfl_xor(sa, o, 64);
            sb += __shfl_xor(sb, o, 64);
            sc += __shfl_xor(sc, o, 64);
        }
        size_t base = (size_t)r * 3 * DD + lane;
        M[base] = __float2half(a / fmaxf(sqrtf(sa), 1e-12f));
        M[base + DD] = __float2half(b / fmaxf(sqrtf(sb), 1e-12f));
        M[base + 2 * DD] = __float2half(c / fmaxf(sqrtf(sc), 1e-12f));
    }
}

// MLP -> interleaved fp16 M at modality mo
template <int K>
__global__ void k_mlp(const float* __restrict__ feat, const float* __restrict__ W,
                      const float* __restrict__ bias, __half* __restrict__ M, int mo) {
    __shared__ float rbuf[4][K];
    int t = threadIdx.x, wib = t >> 6, lane = t & 63;
    float Wr[K];
#pragma unroll
    for (int k4 = 0; k4 < K / 4; k4++) {
        float4 w4 = *(const float4*)(W + (size_t)lane * K + k4 * 4);
        Wr[k4 * 4 + 0] = w4.x;
        Wr[k4 * 4 + 1] = w4.y;
        Wr[k4 * 4 + 2] = w4.z;
        Wr[k4 * 4 + 3] = w4.w;
    }
    float b = bias[lane];
    for (int r = blockIdx.x * 4 + wib; r < NITEM; r += gridDim.x * 4) {
        for (int k = lane; k < K; k += 64) rbuf[wib][k] = feat[(size_t)r * K + k];
        asm volatile("s_waitcnt lgkmcnt(0)" ::: "memory");
        float acc = b;
#pragma unroll
        for (int k4 = 0; k4 < K / 4; k4++) {
            float4 xq = *(const float4*)&rbuf[wib][k4 * 4];
            acc += xq.x * Wr[k4 * 4] + xq.y * Wr[k4 * 4 + 1] + xq.z * Wr[k4 * 4 + 2] +
                   xq.w * Wr[k4 * 4 + 3];
        }
        float h = acc > 0.f ? acc : 0.01f * acc;
        float n = sqrtf(wsum(h * h));
        M[((size_t)(NUSER + r) * 3 + mo) * DD + lane] = __float2half(h / fmaxf(n, 1e-12f));
    }
}

// ---------------- GEMMs (W column in VGPRs, row broadcast via LDS) ----------------
// fp16 interleaved-3 input -> fp16 interleaved-3 output, blockIdx.y = mo
__global__ void k_gemm_h3(const __half* __restrict__ x3, const float* __restrict__ W3,
                          __half* __restrict__ o3) {
    __shared__ float rowbuf[4][DD];
    int mo = blockIdx.y;
    const float* W = W3 + (size_t)mo * 4096;
    int t = threadIdx.x, wib = t >> 6, lane = t & 63;
    float Wc[DD];
#pragma unroll
    for (int k = 0; k < DD; k++) Wc[k] = W[k * DD + lane];
    for (int r = blockIdx.x * 4 + wib; r < NN; r += gridDim.x * 4) {
        size_t idx = ((size_t)r * 3 + mo) * DD + lane;
        rowbuf[wib][lane] = __half2float(x3[idx]);
        asm volatile("s_waitcnt lgkmcnt(0)" ::: "memory");
        float acc = 0.f;
#pragma unroll
        for (int k4 = 0; k4 < DD / 4; k4++) {
            float4 xq = *(const float4*)&rowbuf[wib][k4 * 4];
            acc += xq.x * Wc[k4 * 4] + xq.y * Wc[k4 * 4 + 1] + xq.z * Wc[k4 * 4 + 2] +
                   xq.w * Wc[k4 * 4 + 3];
        }
        o3[idx] = __float2half(acc);
    }
}

// fp32 interleaved-3 input -> fp16 interleaved-3 output
__global__ void k_gemm_f3(const float* __restrict__ x3, const float* __restrict__ W3,
                          __half* __restrict__ o3) {
    __shared__ float rowbuf[4][DD];
    int mo = blockIdx.y;
    const float* W = W3 + (size_t)mo * 4096;
    int t = threadIdx.x, wib = t >> 6, lane = t & 63;
    float Wc[DD];
#pragma unroll
    for (int k = 0; k < DD; k++) Wc[k] = W[k * DD + lane];
    for (int r = blockIdx.x * 4 + wib; r < NN; r += gridDim.x * 4) {
        size_t idx = ((size_t)r * 3 + mo) * DD + lane;
        rowbuf[wib][lane] = x3[idx];
        asm volatile("s_waitcnt lgkmcnt(0)" ::: "memory");
        float acc = 0.f;
#pragma unroll
        for (int k4 = 0; k4 < DD / 4; k4++) {
            float4 xq = *(const float4*)&rowbuf[wib][k4 * 4];
            acc += xq.x * Wc[k4 * 4] + xq.y * Wc[k4 * 4 + 1] + xq.z * Wc[k4 * 4 + 2] +
                   xq.w * Wc[k4 * 4 + 3];
        }
        o3[idx] = __float2half(acc);
    }
}

// fp32 flat input -> fp16 interleaved-2 output (gcn W1/W2 pair), blockIdx.y in {0,1}
__global__ void k_gemm_f2(const float* __restrict__ x, const float* __restrict__ W2,
                          __half* __restrict__ o2) {
    __shared__ float rowbuf[4][DD];
    int mo = blockIdx.y;
    const float* W = W2 + (size_t)mo * 4096;
    int t = threadIdx.x, wib = t >> 6, lane = t & 63;
    float Wc[DD];
#pragma unroll
    for (int k = 0; k < DD; k++) Wc[k] = W[k * DD + lane];
    for (int r = blockIdx.x * 4 + wib; r < NN; r += gridDim.x * 4) {
        rowbuf[wib][lane] = x[(size_t)r * DD + lane];
        asm volatile("s_waitcnt lgkmcnt(0)" ::: "memory");
        float acc = 0.f;
#pragma unroll
        for (int k4 = 0; k4 < DD / 4; k4++) {
            float4 xq = *(const float4*)&rowbuf[wib][k4 * 4];
            acc += xq.x * Wc[k4 * 4] + xq.y * Wc[k4 * 4 + 1] + xq.z * Wc[k4 * 4 + 2] +
                   xq.w * Wc[k4 * 4 + 3];
        }
        o2[((size_t)r * 2 + mo) * DD + lane] = __float2half(acc);
    }
}

// id_emb: l2norm -> x0 (fp32 flat), gemm(gcn_w0) -> g1 (fp16 flat)
__global__ void k_gemm_id(const float* __restrict__ x, const float* __restrict__ W,
                          __half* __restrict__ hout, float* __restrict__ xnorm) {
    __shared__ float rowbuf[4][DD];
    int t = threadIdx.x, wib = t >> 6, lane = t & 63;
    float Wc[DD];
#pragma unroll
    for (int k = 0; k < DD; k++) Wc[k] = W[k * DD + lane];
    for (int r = blockIdx.x * 4 + wib; r < NN; r += gridDim.x * 4) {
        float xv = x[(size_t)r * DD + lane];
        float n = sqrtf(wsum(xv * xv));
        xv /= fmaxf(n, 1e-12f);
        xnorm[(size_t)r * DD + lane] = xv;
        rowbuf[wib][lane] = xv;
        asm volatile("s_waitcnt lgkmcnt(0)" ::: "memory");
        float acc = 0.f;
#pragma unroll
        for (int k4 = 0; k4 < DD / 4; k4++) {
            float4 xq = *(const float4*)&rowbuf[wib][k4 * 4];
            acc += xq.x * Wc[k4 * 4] + xq.y * Wc[k4 * 4 + 1] + xq.z * Wc[k4 * 4 + 2] +
                   xq.w * Wc[k4 * 4 + 3];
        }
        hout[(size_t)r * DD + lane] = __float2half(acc);
    }
}

// ---------------- edge gate factors (fused 3 tables, fp16 gathers) ----------------
__device__ __forceinline__ float gatef(float ssum) {
    float gate = 1.f / (1.f + __expf(-0.5f * ssum));
    return gate > 0.5f ? gate : 1.f;
}

__global__ void k_edgedot3(const __half* __restrict__ M, const int* __restrict__ rp,
                           const int* __restrict__ col, __half* __restrict__ gf4) {
    int t = blockIdx.x * blockDim.x + threadIdx.x;
    int w = t >> 6, lane = t & 63, nw = (gridDim.x * blockDim.x) >> 6;
    int g = lane >> 4, q = lane & 15;
    for (int n = w; n < NN; n += nw) {
        int e0 = rp[n], e1 = rp[n + 1];
        if (e0 == e1) continue;
        size_t db = (size_t)n * 192 + q * 4;
        float4 tv = h4_to_f4(*(const uint2*)(M + db));
        float4 ta = h4_to_f4(*(const uint2*)(M + db + 64));
        float4 tt = h4_to_f4(*(const uint2*)(M + db + 128));
        for (int eb = e0 + g; eb < e1; eb += 4) {
            int sn = col[eb];
            size_t sb = (size_t)sn * 192 + q * 4;
            float4 sv = h4_to_f4(*(const uint2*)(M + sb));
            float4 sa = h4_to_f4(*(const uint2*)(M + sb + 64));
            float4 st = h4_to_f4(*(const uint2*)(M + sb + 128));
            float dv = dot4(tv, sv), da = dot4(ta, sa), dt = dot4(tt, st);
#pragma unroll
            for (int o = 1; o <= 8; o <<= 1) {
                dv += __shfl_xor(dv, o, 64);
                da += __shfl_xor(da, o, 64);
                dt += __shfl_xor(dt, o, 64);
            }
            if (q == 0) {
                HU p01, p2;
                p01.h = __floats2half2_rn(gatef(da + dt), gatef(dv + dt));
                p2.h = __floats2half2_rn(gatef(da + dv), 0.f);
                *(uint2*)(gf4 + (size_t)eb * 4) = make_uint2(p01.u, p2.u);
            }
        }
    }
}

// ---------------- fused 3-modality GAT pre ----------------
__global__ void k_gat_pre3(const __half* __restrict__ h3, const __half* __restrict__ gf4,
                           const int* __restrict__ rp, const int* __restrict__ col,
                           float* __restrict__ x3) {
    int t = blockIdx.x * blockDim.x + threadIdx.x;
    int w = t >> 6, lane = t & 63, nw = (gridDim.x * blockDim.x) >> 6;
    int g = lane >> 4, q = lane & 15;
    for (int n = w; n < NN; n += nw) {
        int e0 = rp[n], e1 = rp[n + 1];
        size_t db = (size_t)n * 192 + q * 4;
        float4 hd0 = h4_to_f4(*(const uint2*)(h3 + db));
        float4 hd1 = h4_to_f4(*(const uint2*)(h3 + db + 64));
        float4 hd2 = h4_to_f4(*(const uint2*)(h3 + db + 128));
        float s0 = 0.f, s1 = 0.f, s2 = 0.f;
        float4 a0 = {0, 0, 0, 0}, a1 = {0, 0, 0, 0}, a2 = {0, 0, 0, 0};
#pragma unroll 2
        for (int eb = e0 + g; eb < e1; eb += 4) {
            int sn = col[eb];
            size_t sb = (size_t)sn * 192 + q * 4;
            float4 v0 = h4_to_f4(*(const uint2*)(h3 + sb));
            float4 v1 = h4_to_f4(*(const uint2*)(h3 + sb + 64));
            float4 v2 = h4_to_f4(*(const uint2*)(h3 + sb + 128));
            uint2 gv = *(const uint2*)(gf4 + (size_t)eb * 4);
            float d0 = dot4(hd0, v0), d1 = dot4(hd1, v1), d2 = dot4(hd2, v2);
#pragma unroll
            for (int o = 1; o <= 8; o <<= 1) {
                d0 += __shfl_xor(d0, o, 64);
                d1 += __shfl_xor(d1, o, 64);
                d2 += __shfl_xor(d2, o, 64);
            }
            HU ga, gb;
            ga.u = gv.x;
            gb.u = gv.y;
            float2 g01 = __half22float2(ga.h);
            float g2 = __half22float2(gb.h).x;
            float sc0 = d0 > 0.f ? d0 : 0.2f * d0;
            float sc1 = d1 > 0.f ? d1 : 0.2f * d1;
            float sc2 = d2 > 0.f ? d2 : 0.2f * d2;
            float p0 = __expf(sc0), p1 = __expf(sc1), p2 = __expf(sc2);
            s0 += p0;
            s1 += p1;
            s2 += p2;
            float pg0 = p0 * g01.x, pg1 = p1 * g01.y, pg2 = p2 * g2;
            a0.x += pg0 * v0.x; a0.y += pg0 * v0.y; a0.z += pg0 * v0.z; a0.w += pg0 * v0.w;
            a1.x += pg1 * v1.x; a1.y += pg1 * v1.y; a1.z += pg1 * v1.z; a1.w += pg1 * v1.w;
            a2.x += pg2 * v2.x; a2.y += pg2 * v2.y; a2.z += pg2 * v2.z; a2.w += pg2 * v2.w;
        }
        s0 = gsum4(s0); s1 = gsum4(s1); s2 = gsum4(s2);
        a0.x = gsum4(a0.x); a0.y = gsum4(a0.y); a0.z = gsum4(a0.z); a0.w = gsum4(a0.w);
        a1.x = gsum4(a1.x); a1.y = gsum4(a1.y); a1.z = gsum4(a1.z); a1.w = gsum4(a1.w);
        a2.x = gsum4(a2.x); a2.y = gsum4(a2.y); a2.z = gsum4(a2.z); a2.w = gsum4(a2.w);
        float i0 = 1.f / (s0 + 1e-16f), i1 = 1.f / (s1 + 1e-16f), i2 = 1.f / (s2 + 1e-16f);
        float4 o0 = {a0.x * i0, a0.y * i0, a0.z * i0, a0.w * i0};
        float4 o1 = {a1.x * i1, a1.y * i1, a1.z * i1, a1.w * i1};
        float4 o2 = {a2.x * i2, a2.y * i2, a2.z * i2, a2.w * i2};
        float n0 = dot4(o0, o0), n1 = dot4(o1, o1), n2 = dot4(o2, o2);
#pragma unroll
        for (int o = 1; o <= 8; o <<= 1) {
            n0 += __shfl_xor(n0, o, 64);
            n1 += __shfl_xor(n1, o, 64);
            n2 += __shfl_xor(n2, o, 64);
        }
        float r0 = 1.f / fmaxf(sqrtf(n0), 1e-12f);
        float r1 = 1.f / fmaxf(sqrtf(n1), 1e-12f);
        float r2 = 1.f / fmaxf(sqrtf(n2), 1e-12f);
        if (g == 0) {
            size_t ob = (size_t)n * 192 + q * 4;
            *(float4*)(x3 + ob) = make_float4(o0.x * r0, o0.y * r0, o0.z * r0, o0.w * r0);
            *(float4*)(x3 + ob + 64) = make_float4(o1.x * r1, o1.y * r1, o1.z * r1, o1.w * r1);
            *(float4*)(x3 + ob + 128) = make_float4(o2.x * r2, o2.y * r2, o2.z * r2, o2.w * r2);
        }
    }
}

// ---------------- fused 3-modality GAT ori (residual + l2norm) ----------------
__global__ void k_gat_ori3(const __half* __restrict__ h3, const float* __restrict__ x3,
                           const int* __restrict__ rp, const int* __restrict__ col,
                           float* __restrict__ ob_, int ostride, int obase) {
    int t = blockIdx.x * blockDim.x + threadIdx.x;
    int w = t >> 6, lane = t & 63, nw = (gridDim.x * blockDim.x) >> 6;
    int g = lane >> 4, q = lane & 15;
    for (int n = w; n < NN; n += nw) {
        int e0 = rp[n], e1 = rp[n + 1];
        size_t db = (size_t)n * 192 + q * 4;
        float4 hd0 = h4_to_f4(*(const uint2*)(h3 + db));
        float4 hd1 = h4_to_f4(*(const uint2*)(h3 + db + 64));
        float4 hd2 = h4_to_f4(*(const uint2*)(h3 + db + 128));
        float s0 = 0.f, s1 = 0.f, s2 = 0.f;
        float4 a0 = {0, 0, 0, 0}, a1 = {0, 0, 0, 0}, a2 = {0, 0, 0, 0};
#pragma unroll 2
        for (int eb = e0 + g; eb < e1; eb += 4) {
            int sn = col[eb];
            size_t sb = (size_t)sn * 192 + q * 4;
            float4 v0 = h4_to_f4(*(const uint2*)(h3 + sb));
            float4 v1 = h4_to_f4(*(const uint2*)(h3 + sb + 64));
            float4 v2 = h4_to_f4(*(const uint2*)(h3 + sb + 128));
            float d0 = dot4(hd0, v0), d1 = dot4(hd1, v1), d2 = dot4(hd2, v2);
#pragma unroll
            for (int o = 1; o <= 8; o <<= 1) {
                d0 += __shfl_xor(d0, o, 64);
                d1 += __shfl_xor(d1, o, 64);
                d2 += __shfl_xor(d2, o, 64);
            }
            float sc0 = d0 > 0.f ? d0 : 0.2f * d0;
            float sc1 = d1 > 0.f ? d1 : 0.2f * d1;
            float sc2 = d2 > 0.f ? d2 : 0.2f * d2;
            float p0 = __expf(sc0), p1 = __expf(sc1), p2 = __expf(sc2);
            s0 += p0;
            s1 += p1;
            s2 += p2;
            a0.x += p0 * v0.x; a0.y += p0 * v0.y; a0.z += p0 * v0.z; a0.w += p0 * v0.w;
            a1.x += p1 * v1.x; a1.y += p1 * v1.y; a1.z += p1 * v1.z; a1.w += p1 * v1.w;
            a2.x += p2 * v2.x; a2.y += p2 * v2.y; a2.z += p2 * v2.z; a2.w += p2 * v2.w;
        }
        s0 = gsum4(s0); s1 = gsum4(s1); s2 = gsum4(s2);
        a0.x = gsum4(a0.x); a0.y = gsum4(a0.y); a0.z = gsum4(a0.z); a0.w = gsum4(a0.w);
        a1.x = gsum4(a1.x); a1.y = gsum4(a1.y); a1.z = gsum4(a1.z); a1.w = gsum4(a1.w);
        a2.x = gsum4(a2.x); a2.y = gsum4(a2.y); a2.z = gsum4(a2.z); a2.w = gsum4(a2.w);
        float i0 = 1.f / (s0 + 1e-16f), i1 = 1.f / (s1 + 1e-16f), i2 = 1.f / (s2 + 1e-16f);
        size_t xb = (size_t)n * 192 + q * 4;
        float4 x0 = *(const float4*)(x3 + xb);
        float4 x1 = *(const float4*)(x3 + xb + 64);
        float4 x2 = *(const float4*)(x3 + xb + 128);
        float4 o0 = {x0.x + a0.x * i0, x0.y + a0.y * i0, x0.z + a0.z * i0, x0.w + a0.w * i0};
        float4 o1 = {x1.x + a1.x * i1, x1.y + a1.y * i1, x1.z + a1.z * i1, x1.w + a1.w * i1};
        float4 o2 = {x2.x + a2.x * i2, x2.y + a2.y * i2, x2.z + a2.z * i2, x2.w + a2.w * i2};
        float n0 = dot4(o0, o0), n1 = dot4(o1, o1), n2 = dot4(o2, o2);
#pragma unroll
        for (int o = 1; o <= 8; o <<= 1) {
            n0 += __shfl_xor(n0, o, 64);
            n1 += __shfl_xor(n1, o, 64);
            n2 += __shfl_xor(n2, o, 64);
        }
        float r0 = 1.f / fmaxf(sqrtf(n0), 1e-12f);
        float r1 = 1.f / fmaxf(sqrtf(n1), 1e-12f);
        float r2 = 1.f / fmaxf(sqrtf(n2), 1e-12f);
        if (g == 0) {
            size_t ob = (size_t)n * ostride + obase + q * 4;
            *(float4*)(ob_ + ob) = make_float4(o0.x * r0, o0.y * r0, o0.z * r0, o0.w * r0);
            *(float4*)(ob_ + ob + 64) = make_float4(o1.x * r1, o1.y * r1, o1.z * r1, o1.w * r1);
            *(float4*)(ob_ + ob + 128) = make_float4(o2.x * r2, o2.y * r2, o2.z * r2, o2.w * r2);
        }
    }
}

// ---------------- GCN ----------------
__global__ void k_gcn1(const __half* __restrict__ h, const int* __restrict__ rp,
                       const int* __restrict__ col, float* __restrict__ out) {
    int t = blockIdx.x * blockDim.x + threadIdx.x;
    int w = t >> 6, lane = t & 63, nw = (gridDim.x * blockDim.x) >> 6;
    int g = lane >> 4, q = lane & 15;
    for (int n = w; n < NN; n += nw) {
        int e0 = rp[n], e1 = rp[n + 1];
        float4 acc = {0, 0, 0, 0};
#pragma unroll 2
        for (int eb = e0 + g; eb < e1; eb += 4) {
            int sn = col[eb];
            float4 hs = h4_to_f4(*(const uint2*)(h + (size_t)sn * DD + q * 4));
            acc.x += hs.x;
            acc.y += hs.y;
            acc.z += hs.z;
            acc.w += hs.w;
        }
        acc.x = gsum4(acc.x);
        acc.y = gsum4(acc.y);
        acc.z = gsum4(acc.z);
        acc.w = gsum4(acc.w);
        if (g == 0) {
            float4 o;
            o.x = acc.x > 0.f ? acc.x : 0.01f * acc.x;
            o.y = acc.y > 0.f ? acc.y : 0.01f * acc.y;
            o.z = acc.z > 0.f ? acc.z : 0.01f * acc.z;
            o.w = acc.w > 0.f ? acc.w : 0.01f * acc.w;
            *(float4*)(out + (size_t)n * DD + q * 4) = o;
        }
    }
}

// fused gcn layers 2+3 + final sum: out[:, :64] = x0 + h1 + leaky(conv(gA)) + conv(gB)
__global__ void k_gcn_final2(const __half* __restrict__ gp, const int* __restrict__ rp,
                             const int* __restrict__ col, const float* __restrict__ x0,
                             const float* __restrict__ h1, float* __restrict__ out) {
    int t = blockIdx.x * blockDim.x + threadIdx.x;
    int w = t >> 6, lane = t & 63, nw = (gridDim.x * blockDim.x) >> 6;
    int g = lane >> 4, q = lane & 15;
    for (int n = w; n < NN; n += nw) {
        int e0 = rp[n], e1 = rp[n + 1];
        float4 aA = {0, 0, 0, 0}, aB = {0, 0, 0, 0};
#pragma unroll 2
        for (int eb = e0 + g; eb < e1; eb += 4) {
            int sn = col[eb];
            size_t sb = (size_t)sn * 128 + q * 4;
            float4 hA = h4_to_f4(*(const uint2*)(gp + sb));
            float4 hB = h4_to_f4(*(const uint2*)(gp + sb + 64));
            aA.x += hA.x; aA.y += hA.y; aA.z += hA.z; aA.w += hA.w;
            aB.x += hB.x; aB.y += hB.y; aB.z += hB.z; aB.w += hB.w;
        }
        aA.x = gsum4(aA.x); aA.y = gsum4(aA.y); aA.z = gsum4(aA.z); aA.w = gsum4(aA.w);
        aB.x = gsum4(aB.x); aB.y = gsum4(aB.y); aB.z = gsum4(aB.z); aB.w = gsum4(aB.w);
        if (g == 0) {
            size_t b = (size_t)n * DD + q * 4;
            float4 v0 = *(const float4*)(x0 + b);
            float4 v1 = *(const float4*)(h1 + b);
            float4 o;
            float h2x = aA.x > 0.f ? aA.x : 0.01f * aA.x;
            float h2y = aA.y > 0.f ? aA.y : 0.01f * aA.y;
            float h2z = aA.z > 0.f ? aA.z : 0.01f * aA.z;
            float h2w = aA.w > 0.f ? aA.w : 0.01f * aA.w;
            o.x = v0.x + v1.x + h2x + aB.x;
            o.y = v0.y + v1.y + h2y + aB.y;
            o.z = v0.z + v1.z + h2z + aB.z;
            o.w = v0.w + v1.w + h2w + aB.w;
            *(float4*)(out + (size_t)n * 256 + q * 4) = o;
        }
    }
}

extern "C" void kernel_launch(void* const* d_in, const int* in_sizes, int n_in,
                              void* d_out, int out_size, void* d_ws, size_t ws_size,
                              hipStream_t stream) {
    const int* ei       = (const int*)d_in[0];
    const float* v_feat = (const float*)d_in[1];
    const float* a_feat = (const float*)d_in[2];
    const float* t_feat = (const float*)d_in[3];
    const float* pref_v = (const float*)d_in[4];
    const float* pref_a = (const float*)d_in[5];
    const float* pref_t = (const float*)d_in[6];
    const float* mlp_v_w = (const float*)d_in[7];
    const float* mlp_v_b = (const float*)d_in[8];
    const float* mlp_a_w = (const float*)d_in[9];
    const float* mlp_a_b = (const float*)d_in[10];
    const float* mlp_t_w = (const float*)d_in[11];
    const float* mlp_t_b = (const float*)d_in[12];
    const float* pre_w  = (const float*)d_in[13];
    const float* ori_w  = (const float*)d_in[14];
    const float* gcn_w  = (const float*)d_in[15];
    const float* id_emb = (const float*)d_in[16];
    float* out = (float*)d_out;

    const int E2 = in_sizes[0];
    const int E  = E2 / 2;

    char* w = (char*)d_ws;
    auto alloc = [&](size_t bytes) -> void* {
        void* p = (void*)w;
        w += (bytes + 255) & ~(size_t)255;
        return p;
    };
    int* cnt  = (int*)alloc((size_t)NN * 4);
    int* rp   = (int*)alloc((size_t)(NN + 1) * 4);
    int* bsum = (int*)alloc(256);
    int* col  = (int*)alloc((size_t)E2 * 4);
    __half* Mh3  = (__half*)alloc(3 * PLANE * 2);   // interleaved [NN][3][64]
    __half* hb3h = (__half*)alloc(3 * PLANE * 2);   // interleaved [NN][3][64]
    float*  x3   = (float*)alloc(3 * PLANE * 4);    // interleaved [NN][3][64]
    __half* gf4  = (__half*)alloc((size_t)E2 * 4 * 2);  // [E2][4] gate factors

    // GCN-phase aliases (gat phase done by then)
    __half* g1 = hb3h;                // [NN][64] fp16
    __half* gpair = hb3h + PLANE;     // [NN][2][64] fp16
    float* x0 = x3;                   // [NN][64] fp32
    float* h1 = x3 + PLANE;           // [NN][64] fp32

    // ---- CSR by destination ----
    const int NBLK = 64, CHUNK = (NN + NBLK - 1) / NBLK;
    hipMemsetAsync(cnt, 0, (size_t)NN * 4, stream);
    k_hist<<<(E2 + 255) / 256, 256, 0, stream>>>(ei, E2, E, cnt);
    k_bsum<<<NBLK, 256, 0, stream>>>(cnt, bsum, NN, CHUNK);
    k_bscan<<<1, 64, 0, stream>>>(bsum, NBLK, rp + NN);
    k_apply<<<NBLK, 256, 0, stream>>>(cnt, bsum, rp, NN, CHUNK);
    hipMemsetAsync(cnt, 0, (size_t)NN * 4, stream);
    k_scatter<<<(E2 + 255) / 256, 256, 0, stream>>>(ei, E2, E, rp, cnt, col);

    // ---- node tables (interleaved fp16) ----
    k_prep_pref<<<640, 256, 0, stream>>>(pref_v, pref_a, pref_t, Mh3);
    k_mlp<128><<<512, 256, 0, stream>>>(v_feat, mlp_v_w, mlp_v_b, Mh3, 0);
    k_mlp<128><<<512, 256, 0, stream>>>(a_feat, mlp_a_w, mlp_a_b, Mh3, 1);
    k_mlp<100><<<512, 256, 0, stream>>>(t_feat, mlp_t_w, mlp_t_b, Mh3, 2);

    const int GB = (NN + 3) / 4;

    // ---- cross-modal gates ----
    k_edgedot3<<<GB, 256, 0, stream>>>(Mh3, rp, col, gf4);

    // ---- 3-modality chains (fused over modalities) ----
    dim3 g3(1280, 3);
    k_gemm_h3<<<g3, 256, 0, stream>>>(Mh3, pre_w, hb3h);
    k_gat_pre3<<<GB, 256, 0, stream>>>(hb3h, gf4, rp, col, x3);
    for (int it = 0; it < 3; it++) {
        k_gemm_f3<<<g3, 256, 0, stream>>>(x3, ori_w, hb3h);
        if (it < 2)
            k_gat_ori3<<<GB, 256, 0, stream>>>(hb3h, x3, rp, col, x3, 192, 0);
        else
            k_gat_ori3<<<GB, 256, 0, stream>>>(hb3h, x3, rp, col, out, 256, 64);
    }

    // ---- real_gcn ----
    k_gemm_id<<<1280, 256, 0, stream>>>(id_emb, gcn_w, g1, x0);
    k_gcn1<<<GB, 256, 0, stream>>>(g1, rp, col, h1);
    dim3 g2(1280, 2);
    k_gemm_f2<<<g2, 256, 0, stream>>>(h1, gcn_w + 4096, gpair);
    k_gcn_final2<<<GB, 256, 0, stream>>>(gpair, rp, col, x0, h1, out);
}

// Round 6
// 738.984 us; speedup vs baseline: 3.3486x; 1.1200x over previous
//
#include <hip/hip_runtime.h>
#include <hip/hip_fp16.h>
#include <math.h>

#define NUSER 10000
#define NITEM 30000
#define NN    40000
#define DD    64
#define PLANE ((size_t)NN * DD)

union HU { unsigned u; __half2 h; };

__device__ __forceinline__ float4 h4_to_f4(uint2 v) {
    HU a, b;
    a.u = v.x;
    b.u = v.y;
    float2 fa = __half22float2(a.h), fb = __half22float2(b.h);
    return make_float4(fa.x, fa.y, fb.x, fb.y);
}

__device__ __forceinline__ float wsum(float v) {
#pragma unroll
    for (int o = 32; o > 0; o >>= 1) v += __shfl_xor(v, o, 64);
    return v;
}
__device__ __forceinline__ float gsum4(float v) {
    v += __shfl_xor(v, 16, 64);
    v += __shfl_xor(v, 32, 64);
    return v;
}
__device__ __forceinline__ float dot4(float4 a, float4 b) {
    return a.x * b.x + a.y * b.y + a.z * b.z + a.w * b.w;
}

// ---------------- CSR build ----------------
__global__ void k_hist(const int* ei, int E2, int E, int* cnt) {
    int i = blockIdx.x * blockDim.x + threadIdx.x;
    if (i >= E2) return;
    int d = (i < E) ? ei[E + i] : ei[i - E];
    atomicAdd(&cnt[d], 1);
}

__global__ void k_bsum(const int* __restrict__ cnt, int* __restrict__ bsum, int n, int chunk) {
    __shared__ int wsh[4];
    int b = blockIdx.x, tid = threadIdx.x;
    int base = b * chunk, end = min(n, base + chunk);
    int s = 0;
    for (int i = base + tid; i < end; i += 256) s += cnt[i];
#pragma unroll
    for (int o = 32; o > 0; o >>= 1) s += __shfl_xor(s, o, 64);
    if ((tid & 63) == 0) wsh[tid >> 6] = s;
    __syncthreads();
    if (tid == 0) bsum[b] = wsh[0] + wsh[1] + wsh[2] + wsh[3];
}

__global__ void k_bscan(int* bsum, int nb, int* rp_end) {
    int lane = threadIdx.x;
    int v = (lane < nb) ? bsum[lane] : 0;
    int orig = v;
#pragma unroll
    for (int o = 1; o < 64; o <<= 1) {
        int y = __shfl_up(v, o, 64);
        if (lane >= o) v += y;
    }
    if (lane < nb) bsum[lane] = v - orig;
    if (lane == 63) *rp_end = v;
}

__global__ void k_apply(const int* __restrict__ cnt, const int* __restrict__ boff,
                        int* __restrict__ rp, int n, int chunk) {
    __shared__ int buf[256];
    __shared__ int csh;
    int b = blockIdx.x, tid = threadIdx.x;
    int base = b * chunk, end = min(n, base + chunk);
    int carry = boff[b];
    for (int t0 = base; t0 < end; t0 += 256) {
        int i = t0 + tid;
        int v = (i < end) ? cnt[i] : 0;
        int x = v;
        buf[tid] = x;
        __syncthreads();
        for (int o = 1; o < 256; o <<= 1) {
            int y = (tid >= o) ? buf[tid - o] : 0;
            __syncthreads();
            x += y;
            buf[tid] = x;
            __syncthreads();
        }
        if (i < end) rp[i] = carry + x - v;
        __syncthreads();
        if (tid == 255) csh = carry + x;
        __syncthreads();
        carry = csh;
    }
}

__global__ void k_scatter(const int* ei, int E2, int E, const int* rp, int* fill, int* col) {
    int i = blockIdx.x * blockDim.x + threadIdx.x;
    if (i >= E2) return;
    int j = (i < E) ? i : i - E;
    int s = (i < E) ? ei[j] : ei[E + j];
    int d = (i < E) ? ei[E + j] : ei[j];
    int pos = rp[d] + atomicAdd(&fill[d], 1);
    col[pos] = s;
}

// ---------------- node prep: 3 prefs -> interleaved fp16 M ----------------
__global__ void k_prep_pref(const float* __restrict__ pv, const float* __restrict__ pa,
                            const float* __restrict__ pt, __half* __restrict__ M) {
    int t = blockIdx.x * blockDim.x + threadIdx.x;
    int w = t >> 6, lane = t & 63, nw = (gridDim.x * blockDim.x) >> 6;
    for (int r = w; r < NUSER; r += nw) {
        float a = pv[(size_t)r * DD + lane];
        float b = pa[(size_t)r * DD + lane];
        float c = pt[(size_t)r * DD + lane];
        float sa = a * a, sb = b * b, sc = c * c;
#pragma unroll
        for (int o = 32; o > 0; o >>= 1) {
            sa += __shfl_xor(sa, o, 64);
            sb += __shfl_xor(sb, o, 64);
            sc += __shfl_xor(sc, o, 64);
        }
        size_t base = (size_t)r * 3 * DD + lane;
        M[base] = __float2half(a / fmaxf(sqrtf(sa), 1e-12f));
        M[base + DD] = __float2half(b / fmaxf(sqrtf(sb), 1e-12f));
        M[base + 2 * DD] = __float2half(c / fmaxf(sqrtf(sc), 1e-12f));
    }
}

// MLP -> interleaved fp16 M at modality mo. W[DD][K] in LDS as float4 [K/4][DD].
// Double-buffered row prefetch; no per-lane W arrays (avoids scratch spill).
template <int K>
__global__ void k_mlp(const float* __restrict__ feat, const float* __restrict__ W,
                      const float* __restrict__ bias, __half* __restrict__ M, int mo) {
    constexpr int K4 = K / 4;
    __shared__ float4 Wl[K4][DD];
    __shared__ float4 rbuf[4][2][K4];
    int t = threadIdx.x, wib = t >> 6, lane = t & 63;
    for (int i = t; i < DD * K4; i += 256) {
        int c = i / K4, k4 = i - c * K4;
        Wl[k4][c] = *(const float4*)(W + (size_t)c * K + k4 * 4);
    }
    __syncthreads();
    float b = bias[lane];
    const int stride = gridDim.x * 4;
    int r = blockIdx.x * 4 + wib;
    float4 v = {0.f, 0.f, 0.f, 0.f};
    if (r < NITEM && lane < K4) v = *(const float4*)(feat + (size_t)r * K + lane * 4);
    int cur = 0;
    for (; r < NITEM; r += stride) {
        if (lane < K4) rbuf[wib][cur][lane] = v;
        int rn = r + stride;
        if (rn < NITEM && lane < K4) v = *(const float4*)(feat + (size_t)rn * K + lane * 4);
        asm volatile("s_waitcnt lgkmcnt(0)" ::: "memory");
        float acc = b;
#pragma unroll
        for (int k4 = 0; k4 < K4; k4++) {
            float4 x4 = rbuf[wib][cur][k4];
            float4 w4 = Wl[k4][lane];
            acc += x4.x * w4.x + x4.y * w4.y + x4.z * w4.z + x4.w * w4.w;
        }
        float h = acc > 0.f ? acc : 0.01f * acc;
        float n = sqrtf(wsum(h * h));
        M[((size_t)(NUSER + r) * 3 + mo) * DD + lane] = __float2half(h / fmaxf(n, 1e-12f));
        cur ^= 1;
    }
}

// ---------------- GEMMs (W column in VGPRs, row broadcast via LDS) ----------------
__global__ void k_gemm_h3(const __half* __restrict__ x3, const float* __restrict__ W3,
                          __half* __restrict__ o3) {
    __shared__ float rowbuf[4][DD];
    int mo = blockIdx.y;
    const float* W = W3 + (size_t)mo * 4096;
    int t = threadIdx.x, wib = t >> 6, lane = t & 63;
    float Wc[DD];
#pragma unroll
    for (int k = 0; k < DD; k++) Wc[k] = W[k * DD + lane];
    for (int r = blockIdx.x * 4 + wib; r < NN; r += gridDim.x * 4) {
        size_t idx = ((size_t)r * 3 + mo) * DD + lane;
        rowbuf[wib][lane] = __half2float(x3[idx]);
        asm volatile("s_waitcnt lgkmcnt(0)" ::: "memory");
        float acc = 0.f;
#pragma unroll
        for (int k4 = 0; k4 < DD / 4; k4++) {
            float4 xq = *(const float4*)&rowbuf[wib][k4 * 4];
            acc += xq.x * Wc[k4 * 4] + xq.y * Wc[k4 * 4 + 1] + xq.z * Wc[k4 * 4 + 2] +
                   xq.w * Wc[k4 * 4 + 3];
        }
        o3[idx] = __float2half(acc);
    }
}

__global__ void k_gemm_f3(const float* __restrict__ x3, const float* __restrict__ W3,
                          __half* __restrict__ o3) {
    __shared__ float rowbuf[4][DD];
    int mo = blockIdx.y;
    const float* W = W3 + (size_t)mo * 4096;
    int t = threadIdx.x, wib = t >> 6, lane = t & 63;
    float Wc[DD];
#pragma unroll
    for (int k = 0; k < DD; k++) Wc[k] = W[k * DD + lane];
    for (int r = blockIdx.x * 4 + wib; r < NN; r += gridDim.x * 4) {
        size_t idx = ((size_t)r * 3 + mo) * DD + lane;
        rowbuf[wib][lane] = x3[idx];
        asm volatile("s_waitcnt lgkmcnt(0)" ::: "memory");
        float acc = 0.f;
#pragma unroll
        for (int k4 = 0; k4 < DD / 4; k4++) {
            float4 xq = *(const float4*)&rowbuf[wib][k4 * 4];
            acc += xq.x * Wc[k4 * 4] + xq.y * Wc[k4 * 4 + 1] + xq.z * Wc[k4 * 4 + 2] +
                   xq.w * Wc[k4 * 4 + 3];
        }
        o3[idx] = __float2half(acc);
    }
}

__global__ void k_gemm_f2(const float* __restrict__ x, const float* __restrict__ W2,
                          __half* __restrict__ o2) {
    __shared__ float rowbuf[4][DD];
    int mo = blockIdx.y;
    const float* W = W2 + (size_t)mo * 4096;
    int t = threadIdx.x, wib = t >> 6, lane = t & 63;
    float Wc[DD];
#pragma unroll
    for (int k = 0; k < DD; k++) Wc[k] = W[k * DD + lane];
    for (int r = blockIdx.x * 4 + wib; r < NN; r += gridDim.x * 4) {
        rowbuf[wib][lane] = x[(size_t)r * DD + lane];
        asm volatile("s_waitcnt lgkmcnt(0)" ::: "memory");
        float acc = 0.f;
#pragma unroll
        for (int k4 = 0; k4 < DD / 4; k4++) {
            float4 xq = *(const float4*)&rowbuf[wib][k4 * 4];
            acc += xq.x * Wc[k4 * 4] + xq.y * Wc[k4 * 4 + 1] + xq.z * Wc[k4 * 4 + 2] +
                   xq.w * Wc[k4 * 4 + 3];
        }
        o2[((size_t)r * 2 + mo) * DD + lane] = __float2half(acc);
    }
}

__global__ void k_gemm_id(const float* __restrict__ x, const float* __restrict__ W,
                          __half* __restrict__ hout, float* __restrict__ xnorm) {
    __shared__ float rowbuf[4][DD];
    int t = threadIdx.x, wib = t >> 6, lane = t & 63;
    float Wc[DD];
#pragma unroll
    for (int k = 0; k < DD; k++) Wc[k] = W[k * DD + lane];
    for (int r = blockIdx.x * 4 + wib; r < NN; r += gridDim.x * 4) {
        float xv = x[(size_t)r * DD + lane];
        float n = sqrtf(wsum(xv * xv));
        xv /= fmaxf(n, 1e-12f);
        xnorm[(size_t)r * DD + lane] = xv;
        rowbuf[wib][lane] = xv;
        asm volatile("s_waitcnt lgkmcnt(0)" ::: "memory");
        float acc = 0.f;
#pragma unroll
        for (int k4 = 0; k4 < DD / 4; k4++) {
            float4 xq = *(const float4*)&rowbuf[wib][k4 * 4];
            acc += xq.x * Wc[k4 * 4] + xq.y * Wc[k4 * 4 + 1] + xq.z * Wc[k4 * 4 + 2] +
                   xq.w * Wc[k4 * 4 + 3];
        }
        hout[(size_t)r * DD + lane] = __float2half(acc);
    }
}

// ---------------- edge gate factors (fused 3 tables, fp16 gathers) ----------------
__device__ __forceinline__ float gatef(float ssum) {
    float gate = 1.f / (1.f + __expf(-0.5f * ssum));
    return gate > 0.5f ? gate : 1.f;
}

__global__ void k_edgedot3(const __half* __restrict__ M, const int* __restrict__ rp,
                           const int* __restrict__ col, __half* __restrict__ gf4) {
    int t = blockIdx.x * blockDim.x + threadIdx.x;
    int w = t >> 6, lane = t & 63, nw = (gridDim.x * blockDim.x) >> 6;
    int g = lane >> 4, q = lane & 15;
    for (int n = w; n < NN; n += nw) {
        int e0 = rp[n], e1 = rp[n + 1];
        if (e0 == e1) continue;
        size_t db = (size_t)n * 192 + q * 4;
        float4 tv = h4_to_f4(*(const uint2*)(M + db));
        float4 ta = h4_to_f4(*(const uint2*)(M + db + 64));
        float4 tt = h4_to_f4(*(const uint2*)(M + db + 128));
        for (int eb = e0 + g; eb < e1; eb += 4) {
            int sn = col[eb];
            size_t sb = (size_t)sn * 192 + q * 4;
            float4 sv = h4_to_f4(*(const uint2*)(M + sb));
            float4 sa = h4_to_f4(*(const uint2*)(M + sb + 64));
            float4 st = h4_to_f4(*(const uint2*)(M + sb + 128));
            float dv = dot4(tv, sv), da = dot4(ta, sa), dt = dot4(tt, st);
#pragma unroll
            for (int o = 1; o <= 8; o <<= 1) {
                dv += __shfl_xor(dv, o, 64);
                da += __shfl_xor(da, o, 64);
                dt += __shfl_xor(dt, o, 64);
            }
            if (q == 0) {
                HU p01, p2;
                p01.h = __floats2half2_rn(gatef(da + dt), gatef(dv + dt));
                p2.h = __floats2half2_rn(gatef(da + dv), 0.f);
                *(uint2*)(gf4 + (size_t)eb * 4) = make_uint2(p01.u, p2.u);
            }
        }
    }
}

// ---------------- fused 3-modality GAT pre ----------------
__global__ void k_gat_pre3(const __half* __restrict__ h3, const __half* __restrict__ gf4,
                           const int* __restrict__ rp, const int* __restrict__ col,
                           float* __restrict__ x3) {
    int t = blockIdx.x * blockDim.x + threadIdx.x;
    int w = t >> 6, lane = t & 63, nw = (gridDim.x * blockDim.x) >> 6;
    int g = lane >> 4, q = lane & 15;
    for (int n = w; n < NN; n += nw) {
        int e0 = rp[n], e1 = rp[n + 1];
        size_t db = (size_t)n * 192 + q * 4;
        float4 hd0 = h4_to_f4(*(const uint2*)(h3 + db));
        float4 hd1 = h4_to_f4(*(const uint2*)(h3 + db + 64));
        float4 hd2 = h4_to_f4(*(const uint2*)(h3 + db + 128));
        float s0 = 0.f, s1 = 0.f, s2 = 0.f;
        float4 a0 = {0, 0, 0, 0}, a1 = {0, 0, 0, 0}, a2 = {0, 0, 0, 0};
#pragma unroll 2
        for (int eb = e0 + g; eb < e1; eb += 4) {
            int sn = col[eb];
            size_t sb = (size_t)sn * 192 + q * 4;
            float4 v0 = h4_to_f4(*(const uint2*)(h3 + sb));
            float4 v1 = h4_to_f4(*(const uint2*)(h3 + sb + 64));
            float4 v2 = h4_to_f4(*(const uint2*)(h3 + sb + 128));
            uint2 gv = *(const uint2*)(gf4 + (size_t)eb * 4);
            float d0 = dot4(hd0, v0), d1 = dot4(hd1, v1), d2 = dot4(hd2, v2);
#pragma unroll
            for (int o = 1; o <= 8; o <<= 1) {
                d0 += __shfl_xor(d0, o, 64);
                d1 += __shfl_xor(d1, o, 64);
                d2 += __shfl_xor(d2, o, 64);
            }
            HU ga, gb;
            ga.u = gv.x;
            gb.u = gv.y;
            float2 g01 = __half22float2(ga.h);
            float g2 = __half22float2(gb.h).x;
            float sc0 = d0 > 0.f ? d0 : 0.2f * d0;
            float sc1 = d1 > 0.f ? d1 : 0.2f * d1;
            float sc2 = d2 > 0.f ? d2 : 0.2f * d2;
            float p0 = __expf(sc0), p1 = __expf(sc1), p2 = __expf(sc2);
            s0 += p0;
            s1 += p1;
            s2 += p2;
            float pg0 = p0 * g01.x, pg1 = p1 * g01.y, pg2 = p2 * g2;
            a0.x += pg0 * v0.x; a0.y += pg0 * v0.y; a0.z += pg0 * v0.z; a0.w += pg0 * v0.w;
            a1.x += pg1 * v1.x; a1.y += pg1 * v1.y; a1.z += pg1 * v1.z; a1.w += pg1 * v1.w;
            a2.x += pg2 * v2.x; a2.y += pg2 * v2.y; a2.z += pg2 * v2.z; a2.w += pg2 * v2.w;
        }
        s0 = gsum4(s0); s1 = gsum4(s1); s2 = gsum4(s2);
        a0.x = gsum4(a0.x); a0.y = gsum4(a0.y); a0.z = gsum4(a0.z); a0.w = gsum4(a0.w);
        a1.x = gsum4(a1.x); a1.y = gsum4(a1.y); a1.z = gsum4(a1.z); a1.w = gsum4(a1.w);
        a2.x = gsum4(a2.x); a2.y = gsum4(a2.y); a2.z = gsum4(a2.z); a2.w = gsum4(a2.w);
        float i0 = 1.f / (s0 + 1e-16f), i1 = 1.f / (s1 + 1e-16f), i2 = 1.f / (s2 + 1e-16f);
        float4 o0 = {a0.x * i0, a0.y * i0, a0.z * i0, a0.w * i0};
        float4 o1 = {a1.x * i1, a1.y * i1, a1.z * i1, a1.w * i1};
        float4 o2 = {a2.x * i2, a2.y * i2, a2.z * i2, a2.w * i2};
        float n0 = dot4(o0, o0), n1 = dot4(o1, o1), n2 = dot4(o2, o2);
#pragma unroll
        for (int o = 1; o <= 8; o <<= 1) {
            n0 += __shfl_xor(n0, o, 64);
            n1 += __shfl_xor(n1, o, 64);
            n2 += __shfl_xor(n2, o, 64);
        }
        float r0 = 1.f / fmaxf(sqrtf(n0), 1e-12f);
        float r1 = 1.f / fmaxf(sqrtf(n1), 1e-12f);
        float r2 = 1.f / fmaxf(sqrtf(n2), 1e-12f);
        if (g == 0) {
            size_t ob = (size_t)n * 192 + q * 4;
            *(float4*)(x3 + ob) = make_float4(o0.x * r0, o0.y * r0, o0.z * r0, o0.w * r0);
            *(float4*)(x3 + ob + 64) = make_float4(o1.x * r1, o1.y * r1, o1.z * r1, o1.w * r1);
            *(float4*)(x3 + ob + 128) = make_float4(o2.x * r2, o2.y * r2, o2.z * r2, o2.w * r2);
        }
    }
}

// ---------------- fused 3-modality GAT ori (residual + l2norm) ----------------
__global__ void k_gat_ori3(const __half* __restrict__ h3, const float* __restrict__ x3,
                           const int* __restrict__ rp, const int* __restrict__ col,
                           float* __restrict__ ob_, int ostride, int obase) {
    int t = blockIdx.x * blockDim.x + threadIdx.x;
    int w = t >> 6, lane = t & 63, nw = (gridDim.x * blockDim.x) >> 6;
    int g = lane >> 4, q = lane & 15;
    for (int n = w; n < NN; n += nw) {
        int e0 = rp[n], e1 = rp[n + 1];
        size_t db = (size_t)n * 192 + q * 4;
        float4 hd0 = h4_to_f4(*(const uint2*)(h3 + db));
        float4 hd1 = h4_to_f4(*(const uint2*)(h3 + db + 64));
        float4 hd2 = h4_to_f4(*(const uint2*)(h3 + db + 128));
        float s0 = 0.f, s1 = 0.f, s2 = 0.f;
        float4 a0 = {0, 0, 0, 0}, a1 = {0, 0, 0, 0}, a2 = {0, 0, 0, 0};
#pragma unroll 2
        for (int eb = e0 + g; eb < e1; eb += 4) {
            int sn = col[eb];
            size_t sb = (size_t)sn * 192 + q * 4;
            float4 v0 = h4_to_f4(*(const uint2*)(h3 + sb));
            float4 v1 = h4_to_f4(*(const uint2*)(h3 + sb + 64));
            float4 v2 = h4_to_f4(*(const uint2*)(h3 + sb + 128));
            float d0 = dot4(hd0, v0), d1 = dot4(hd1, v1), d2 = dot4(hd2, v2);
#pragma unroll
            for (int o = 1; o <= 8; o <<= 1) {
                d0 += __shfl_xor(d0, o, 64);
                d1 += __shfl_xor(d1, o, 64);
                d2 += __shfl_xor(d2, o, 64);
            }
            float sc0 = d0 > 0.f ? d0 : 0.2f * d0;
            float sc1 = d1 > 0.f ? d1 : 0.2f * d1;
            float sc2 = d2 > 0.f ? d2 : 0.2f * d2;
            float p0 = __expf(sc0), p1 = __expf(sc1), p2 = __expf(sc2);
            s0 += p0;
            s1 += p1;
            s2 += p2;
            a0.x += p0 * v0.x; a0.y += p0 * v0.y; a0.z += p0 * v0.z; a0.w += p0 * v0.w;
            a1.x += p1 * v1.x; a1.y += p1 * v1.y; a1.z += p1 * v1.z; a1.w += p1 * v1.w;
            a2.x += p2 * v2.x; a2.y += p2 * v2.y; a2.z += p2 * v2.z; a2.w += p2 * v2.w;
        }
        s0 = gsum4(s0); s1 = gsum4(s1); s2 = gsum4(s2);
        a0.x = gsum4(a0.x); a0.y = gsum4(a0.y); a0.z = gsum4(a0.z); a0.w = gsum4(a0.w);
        a1.x = gsum4(a1.x); a1.y = gsum4(a1.y); a1.z = gsum4(a1.z); a1.w = gsum4(a1.w);
        a2.x = gsum4(a2.x); a2.y = gsum4(a2.y); a2.z = gsum4(a2.z); a2.w = gsum4(a2.w);
        float i0 = 1.f / (s0 + 1e-16f), i1 = 1.f / (s1 + 1e-16f), i2 = 1.f / (s2 + 1e-16f);
        size_t xb = (size_t)n * 192 + q * 4;
        float4 x0 = *(const float4*)(x3 + xb);
        float4 x1 = *(const float4*)(x3 + xb + 64);
        float4 x2 = *(const float4*)(x3 + xb + 128);
        float4 o0 = {x0.x + a0.x * i0, x0.y + a0.y * i0, x0.z + a0.z * i0, x0.w + a0.w * i0};
        float4 o1 = {x1.x + a1.x * i1, x1.y + a1.y * i1, x1.z + a1.z * i1, x1.w + a1.w * i1};
        float4 o2 = {x2.x + a2.x * i2, x2.y + a2.y * i2, x2.z + a2.z * i2, x2.w + a2.w * i2};
        float n0 = dot4(o0, o0), n1 = dot4(o1, o1), n2 = dot4(o2, o2);
#pragma unroll
        for (int o = 1; o <= 8; o <<= 1) {
            n0 += __shfl_xor(n0, o, 64);
            n1 += __shfl_xor(n1, o, 64);
            n2 += __shfl_xor(n2, o, 64);
        }
        float r0 = 1.f / fmaxf(sqrtf(n0), 1e-12f);
        float r1 = 1.f / fmaxf(sqrtf(n1), 1e-12f);
        float r2 = 1.f / fmaxf(sqrtf(n2), 1e-12f);
        if (g == 0) {
            size_t ob = (size_t)n * ostride + obase + q * 4;
            *(float4*)(ob_ + ob) = make_float4(o0.x * r0, o0.y * r0, o0.z * r0, o0.w * r0);
            *(float4*)(ob_ + ob + 64) = make_float4(o1.x * r1, o1.y * r1, o1.z * r1, o1.w * r1);
            *(float4*)(ob_ + ob + 128) = make_float4(o2.x * r2, o2.y * r2, o2.z * r2, o2.w * r2);
        }
    }
}

// ---------------- GCN ----------------
__global__ void k_gcn1(const __half* __restrict__ h, const int* __restrict__ rp,
                       const int* __restrict__ col, float* __restrict__ out) {
    int t = blockIdx.x * blockDim.x + threadIdx.x;
    int w = t >> 6, lane = t & 63, nw = (gridDim.x * blockDim.x) >> 6;
    int g = lane >> 4, q = lane & 15;
    for (int n = w; n < NN; n += nw) {
        int e0 = rp[n], e1 = rp[n + 1];
        float4 acc = {0, 0, 0, 0};
#pragma unroll 2
        for (int eb = e0 + g; eb < e1; eb += 4) {
            int sn = col[eb];
            float4 hs = h4_to_f4(*(const uint2*)(h + (size_t)sn * DD + q * 4));
            acc.x += hs.x;
            acc.y += hs.y;
            acc.z += hs.z;
            acc.w += hs.w;
        }
        acc.x = gsum4(acc.x);
        acc.y = gsum4(acc.y);
        acc.z = gsum4(acc.z);
        acc.w = gsum4(acc.w);
        if (g == 0) {
            float4 o;
            o.x = acc.x > 0.f ? acc.x : 0.01f * acc.x;
            o.y = acc.y > 0.f ? acc.y : 0.01f * acc.y;
            o.z = acc.z > 0.f ? acc.z : 0.01f * acc.z;
            o.w = acc.w > 0.f ? acc.w : 0.01f * acc.w;
            *(float4*)(out + (size_t)n * DD + q * 4) = o;
        }
    }
}

__global__ void k_gcn_final2(const __half* __restrict__ gp, const int* __restrict__ rp,
                             const int* __restrict__ col, const float* __restrict__ x0,
                             const float* __restrict__ h1, float* __restrict__ out) {
    int t = blockIdx.x * blockDim.x + threadIdx.x;
    int w = t >> 6, lane = t & 63, nw = (gridDim.x * blockDim.x) >> 6;
    int g = lane >> 4, q = lane & 15;
    for (int n = w; n < NN; n += nw) {
        int e0 = rp[n], e1 = rp[n + 1];
        float4 aA = {0, 0, 0, 0}, aB = {0, 0, 0, 0};
#pragma unroll 2
        for (int eb = e0 + g; eb < e1; eb += 4) {
            int sn = col[eb];
            size_t sb = (size_t)sn * 128 + q * 4;
            float4 hA = h4_to_f4(*(const uint2*)(gp + sb));
            float4 hB = h4_to_f4(*(const uint2*)(gp + sb + 64));
            aA.x += hA.x; aA.y += hA.y; aA.z += hA.z; aA.w += hA.w;
            aB.x += hB.x; aB.y += hB.y; aB.z += hB.z; aB.w += hB.w;
        }
        aA.x = gsum4(aA.x); aA.y = gsum4(aA.y); aA.z = gsum4(aA.z); aA.w = gsum4(aA.w);
        aB.x = gsum4(aB.x); aB.y = gsum4(aB.y); aB.z = gsum4(aB.z); aB.w = gsum4(aB.w);
        if (g == 0) {
            size_t b = (size_t)n * DD + q * 4;
            float4 v0 = *(const float4*)(x0 + b);
            float4 v1 = *(const float4*)(h1 + b);
            float4 o;
            float h2x = aA.x > 0.f ? aA.x : 0.01f * aA.x;
            float h2y = aA.y > 0.f ? aA.y : 0.01f * aA.y;
            float h2z = aA.z > 0.f ? aA.z : 0.01f * aA.z;
            float h2w = aA.w > 0.f ? aA.w : 0.01f * aA.w;
            o.x = v0.x + v1.x + h2x + aB.x;
            o.y = v0.y + v1.y + h2y + aB.y;
            o.z = v0.z + v1.z + h2z + aB.z;
            o.w = v0.w + v1.w + h2w + aB.w;
            *(float4*)(out + (size_t)n * 256 + q * 4) = o;
        }
    }
}

extern "C" void kernel_launch(void* const* d_in, const int* in_sizes, int n_in,
                              void* d_out, int out_size, void* d_ws, size_t ws_size,
                              hipStream_t stream) {
    const int* ei       = (const int*)d_in[0];
    const float* v_feat = (const float*)d_in[1];
    const float* a_feat = (const float*)d_in[2];
    const float* t_feat = (const float*)d_in[3];
    const float* pref_v = (const float*)d_in[4];
    const float* pref_a = (const float*)d_in[5];
    const float* pref_t = (const float*)d_in[6];
    const float* mlp_v_w = (const float*)d_in[7];
    const float* mlp_v_b = (const float*)d_in[8];
    const float* mlp_a_w = (const float*)d_in[9];
    const float* mlp_a_b = (const float*)d_in[10];
    const float* mlp_t_w = (const float*)d_in[11];
    const float* mlp_t_b = (const float*)d_in[12];
    const float* pre_w  = (const float*)d_in[13];
    const float* ori_w  = (const float*)d_in[14];
    const float* gcn_w  = (const float*)d_in[15];
    const float* id_emb = (const float*)d_in[16];
    float* out = (float*)d_out;

    const int E2 = in_sizes[0];
    const int E  = E2 / 2;

    char* w = (char*)d_ws;
    auto alloc = [&](size_t bytes) -> void* {
        void* p = (void*)w;
        w += (bytes + 255) & ~(size_t)255;
        return p;
    };
    int* cnt  = (int*)alloc((size_t)NN * 4);
    int* rp   = (int*)alloc((size_t)(NN + 1) * 4);
    int* bsum = (int*)alloc(256);
    int* col  = (int*)alloc((size_t)E2 * 4);
    __half* Mh3  = (__half*)alloc(3 * PLANE * 2);
    __half* hb3h = (__half*)alloc(3 * PLANE * 2);
    float*  x3   = (float*)alloc(3 * PLANE * 4);
    __half* gf4  = (__half*)alloc((size_t)E2 * 4 * 2);

    __half* g1 = hb3h;
    __half* gpair = hb3h + PLANE;
    float* x0 = x3;
    float* h1 = x3 + PLANE;

    // ---- CSR by destination ----
    const int NBLK = 64, CHUNK = (NN + NBLK - 1) / NBLK;
    hipMemsetAsync(cnt, 0, (size_t)NN * 4, stream);
    k_hist<<<(E2 + 255) / 256, 256, 0, stream>>>(ei, E2, E, cnt);
    k_bsum<<<NBLK, 256, 0, stream>>>(cnt, bsum, NN, CHUNK);
    k_bscan<<<1, 64, 0, stream>>>(bsum, NBLK, rp + NN);
    k_apply<<<NBLK, 256, 0, stream>>>(cnt, bsum, rp, NN, CHUNK);
    hipMemsetAsync(cnt, 0, (size_t)NN * 4, stream);
    k_scatter<<<(E2 + 255) / 256, 256, 0, stream>>>(ei, E2, E, rp, cnt, col);

    // ---- node tables (interleaved fp16) ----
    k_prep_pref<<<640, 256, 0, stream>>>(pref_v, pref_a, pref_t, Mh3);
    k_mlp<128><<<1024, 256, 0, stream>>>(v_feat, mlp_v_w, mlp_v_b, Mh3, 0);
    k_mlp<128><<<1024, 256, 0, stream>>>(a_feat, mlp_a_w, mlp_a_b, Mh3, 1);
    k_mlp<100><<<1024, 256, 0, stream>>>(t_feat, mlp_t_w, mlp_t_b, Mh3, 2);

    const int GB = (NN + 3) / 4;

    // ---- cross-modal gates ----
    k_edgedot3<<<GB, 256, 0, stream>>>(Mh3, rp, col, gf4);

    // ---- 3-modality chains (fused over modalities) ----
    dim3 g3(1280, 3);
    k_gemm_h3<<<g3, 256, 0, stream>>>(Mh3, pre_w, hb3h);
    k_gat_pre3<<<GB, 256, 0, stream>>>(hb3h, gf4, rp, col, x3);
    for (int it = 0; it < 3; it++) {
        k_gemm_f3<<<g3, 256, 0, stream>>>(x3, ori_w, hb3h);
        if (it < 2)
            k_gat_ori3<<<GB, 256, 0, stream>>>(hb3h, x3, rp, col, x3, 192, 0);
        else
            k_gat_ori3<<<GB, 256, 0, stream>>>(hb3h, x3, rp, col, out, 256, 64);
    }

    // ---- real_gcn ----
    k_gemm_id<<<1280, 256, 0, stream>>>(id_emb, gcn_w, g1, x0);
    k_gcn1<<<GB, 256, 0, stream>>>(g1, rp, col, h1);
    dim3 g2(1280, 2);
    k_gemm_f2<<<g2, 256, 0, stream>>>(h1, gcn_w + 4096, gpair);
    k_gcn_final2<<<GB, 256, 0, stream>>>(gpair, rp, col, x0, h1, out);
}

// Round 7
// 661.537 us; speedup vs baseline: 3.7406x; 1.1171x over previous
//
#include <hip/hip_runtime.h>
#include <hip/hip_fp16.h>
#include <math.h>

#define NUSER 10000
#define NITEM 30000
#define NN    40000
#define DD    64
#define PLANE ((size_t)NN * DD)

typedef _Float16 hv2 __attribute__((ext_vector_type(2)));
union U2H { unsigned u; hv2 v; __half2 hh; };

#if defined(__has_builtin)
#if __has_builtin(__builtin_amdgcn_fdot2)
#define HAS_FDOT2 1
#endif
#endif

__device__ __forceinline__ float fdot2u(unsigned a, unsigned b, float c) {
#ifdef HAS_FDOT2
    U2H x, y;
    x.u = a;
    y.u = b;
    return __builtin_amdgcn_fdot2(x.v, y.v, c, false);
#else
    U2H x, y;
    x.u = a;
    y.u = b;
    float2 fa = __half22float2(x.hh), fb = __half22float2(y.hh);
    return c + fa.x * fb.x + fa.y * fb.y;
#endif
}

__device__ __forceinline__ float dot8(uint4 a, uint4 b) {
    float d = fdot2u(a.x, b.x, 0.f);
    d = fdot2u(a.y, b.y, d);
    d = fdot2u(a.z, b.z, d);
    d = fdot2u(a.w, b.w, d);
    return d;
}

__device__ __forceinline__ __half2 uh(unsigned u) { U2H x; x.u = u; return x.hh; }
__device__ __forceinline__ unsigned hu(__half2 h) { U2H x; x.hh = h; return x.u; }
__device__ __forceinline__ __half2 h2rx(__half2 v, int m) {
    return __hadd2(v, uh((unsigned)__shfl_xor((int)hu(v), m, 64)));
}

__device__ __forceinline__ float wsum(float v) {
#pragma unroll
    for (int o = 32; o > 0; o >>= 1) v += __shfl_xor(v, o, 64);
    return v;
}
// reduce across the 8 dim-lanes (bits 0..2)
__device__ __forceinline__ float qsum8(float v) {
    v += __shfl_xor(v, 1, 64);
    v += __shfl_xor(v, 2, 64);
    v += __shfl_xor(v, 4, 64);
    return v;
}
// reduce across the 8 edge-groups (bits 3..5)
__device__ __forceinline__ float gsum8(float v) {
    v += __shfl_xor(v, 8, 64);
    v += __shfl_xor(v, 16, 64);
    v += __shfl_xor(v, 32, 64);
    return v;
}

// block-balanced node order: [user, item, item, item] repeating
__device__ __forceinline__ int nodeperm(int i) {
    return ((i & 3) == 0) ? (i >> 2) : (NUSER + i - 1 - (i >> 2));
}

// ---------------- CSR build ----------------
__global__ void k_hist(const int* ei, int E2, int E, int* cnt) {
    int i = blockIdx.x * blockDim.x + threadIdx.x;
    if (i >= E2) return;
    int d = (i < E) ? ei[E + i] : ei[i - E];
    atomicAdd(&cnt[d], 1);
}

__global__ void k_bsum(const int* __restrict__ cnt, int* __restrict__ bsum, int n, int chunk) {
    __shared__ int wsh[4];
    int b = blockIdx.x, tid = threadIdx.x;
    int base = b * chunk, end = min(n, base + chunk);
    int s = 0;
    for (int i = base + tid; i < end; i += 256) s += cnt[i];
#pragma unroll
    for (int o = 32; o > 0; o >>= 1) s += __shfl_xor(s, o, 64);
    if ((tid & 63) == 0) wsh[tid >> 6] = s;
    __syncthreads();
    if (tid == 0) bsum[b] = wsh[0] + wsh[1] + wsh[2] + wsh[3];
}

__global__ void k_bscan(int* bsum, int nb, int* rp_end) {
    int lane = threadIdx.x;
    int v = (lane < nb) ? bsum[lane] : 0;
    int orig = v;
#pragma unroll
    for (int o = 1; o < 64; o <<= 1) {
        int y = __shfl_up(v, o, 64);
        if (lane >= o) v += y;
    }
    if (lane < nb) bsum[lane] = v - orig;
    if (lane == 63) *rp_end = v;
}

__global__ void k_apply(const int* __restrict__ cnt, const int* __restrict__ boff,
                        int* __restrict__ rp, int n, int chunk) {
    __shared__ int buf[256];
    __shared__ int csh;
    int b = blockIdx.x, tid = threadIdx.x;
    int base = b * chunk, end = min(n, base + chunk);
    int carry = boff[b];
    for (int t0 = base; t0 < end; t0 += 256) {
        int i = t0 + tid;
        int v = (i < end) ? cnt[i] : 0;
        int x = v;
        buf[tid] = x;
        __syncthreads();
        for (int o = 1; o < 256; o <<= 1) {
            int y = (tid >= o) ? buf[tid - o] : 0;
            __syncthreads();
            x += y;
            buf[tid] = x;
            __syncthreads();
        }
        if (i < end) rp[i] = carry + x - v;
        __syncthreads();
        if (tid == 255) csh = carry + x;
        __syncthreads();
        carry = csh;
    }
}

__global__ void k_scatter(const int* ei, int E2, int E, const int* rp, int* fill, int* col) {
    int i = blockIdx.x * blockDim.x + threadIdx.x;
    if (i >= E2) return;
    int j = (i < E) ? i : i - E;
    int s = (i < E) ? ei[j] : ei[E + j];
    int d = (i < E) ? ei[E + j] : ei[j];
    int pos = rp[d] + atomicAdd(&fill[d], 1);
    col[pos] = s;
}

// ---------------- node prep ----------------
__global__ void k_prep_pref(const float* __restrict__ pv, const float* __restrict__ pa,
                            const float* __restrict__ pt, __half* __restrict__ M) {
    int t = blockIdx.x * blockDim.x + threadIdx.x;
    int w = t >> 6, lane = t & 63, nw = (gridDim.x * blockDim.x) >> 6;
    for (int r = w; r < NUSER; r += nw) {
        float a = pv[(size_t)r * DD + lane];
        float b = pa[(size_t)r * DD + lane];
        float c = pt[(size_t)r * DD + lane];
        float sa = a * a, sb = b * b, sc = c * c;
#pragma unroll
        for (int o = 32; o > 0; o >>= 1) {
            sa += __shfl_xor(sa, o, 64);
            sb += __shfl_xor(sb, o, 64);
            sc += __shfl_xor(sc, o, 64);
        }
        size_t base = (size_t)r * 3 * DD + lane;
        M[base] = __float2half(a / fmaxf(sqrtf(sa), 1e-12f));
        M[base + DD] = __float2half(b / fmaxf(sqrtf(sb), 1e-12f));
        M[base + 2 * DD] = __float2half(c / fmaxf(sqrtf(sc), 1e-12f));
    }
}

template <int K>
__global__ void k_mlp(const float* __restrict__ feat, const float* __restrict__ W,
                      const float* __restrict__ bias, __half* __restrict__ M, int mo) {
    constexpr int K4 = K / 4;
    __shared__ float4 Wl[K4][DD];
    __shared__ float4 rbuf[4][2][K4];
    int t = threadIdx.x, wib = t >> 6, lane = t & 63;
    for (int i = t; i < DD * K4; i += 256) {
        int c = i / K4, k4 = i - c * K4;
        Wl[k4][c] = *(const float4*)(W + (size_t)c * K + k4 * 4);
    }
    __syncthreads();
    float b = bias[lane];
    const int stride = gridDim.x * 4;
    int r = blockIdx.x * 4 + wib;
    float4 v = {0.f, 0.f, 0.f, 0.f};
    if (r < NITEM && lane < K4) v = *(const float4*)(feat + (size_t)r * K + lane * 4);
    int cur = 0;
    for (; r < NITEM; r += stride) {
        if (lane < K4) rbuf[wib][cur][lane] = v;
        int rn = r + stride;
        if (rn < NITEM && lane < K4) v = *(const float4*)(feat + (size_t)rn * K + lane * 4);
        asm volatile("s_waitcnt lgkmcnt(0)" ::: "memory");
        float acc = b;
#pragma unroll
        for (int k4 = 0; k4 < K4; k4++) {
            float4 x4 = rbuf[wib][cur][k4];
            float4 w4 = Wl[k4][lane];
            acc += x4.x * w4.x + x4.y * w4.y + x4.z * w4.z + x4.w * w4.w;
        }
        float h = acc > 0.f ? acc : 0.01f * acc;
        float n = sqrtf(wsum(h * h));
        M[((size_t)(NUSER + r) * 3 + mo) * DD + lane] = __float2half(h / fmaxf(n, 1e-12f));
        cur ^= 1;
    }
}

// ---------------- GEMM: fp16 interleaved-3 in -> fp16 interleaved-3 out ----------------
__global__ void k_gemm_h3(const __half* __restrict__ x3, const float* __restrict__ W3,
                          __half* __restrict__ o3) {
    __shared__ float rowbuf[4][DD];
    int mo = blockIdx.y;
    const float* W = W3 + (size_t)mo * 4096;
    int t = threadIdx.x, wib = t >> 6, lane = t & 63;
    float Wc[DD];
#pragma unroll
    for (int k = 0; k < DD; k++) Wc[k] = W[k * DD + lane];
    for (int r = blockIdx.x * 4 + wib; r < NN; r += gridDim.x * 4) {
        size_t idx = ((size_t)r * 3 + mo) * DD + lane;
        rowbuf[wib][lane] = __half2float(x3[idx]);
        asm volatile("s_waitcnt lgkmcnt(0)" ::: "memory");
        float acc = 0.f;
#pragma unroll
        for (int k4 = 0; k4 < DD / 4; k4++) {
            float4 xq = *(const float4*)&rowbuf[wib][k4 * 4];
            acc += xq.x * Wc[k4 * 4] + xq.y * Wc[k4 * 4 + 1] + xq.z * Wc[k4 * 4 + 2] +
                   xq.w * Wc[k4 * 4 + 3];
        }
        o3[idx] = __float2half(acc);
    }
}

__global__ void k_gemm_f2(const float* __restrict__ x, const float* __restrict__ W2,
                          __half* __restrict__ o2) {
    __shared__ float rowbuf[4][DD];
    int mo = blockIdx.y;
    const float* W = W2 + (size_t)mo * 4096;
    int t = threadIdx.x, wib = t >> 6, lane = t & 63;
    float Wc[DD];
#pragma unroll
    for (int k = 0; k < DD; k++) Wc[k] = W[k * DD + lane];
    for (int r = blockIdx.x * 4 + wib; r < NN; r += gridDim.x * 4) {
        rowbuf[wib][lane] = x[(size_t)r * DD + lane];
        asm volatile("s_waitcnt lgkmcnt(0)" ::: "memory");
        float acc = 0.f;
#pragma unroll
        for (int k4 = 0; k4 < DD / 4; k4++) {
            float4 xq = *(const float4*)&rowbuf[wib][k4 * 4];
            acc += xq.x * Wc[k4 * 4] + xq.y * Wc[k4 * 4 + 1] + xq.z * Wc[k4 * 4 + 2] +
                   xq.w * Wc[k4 * 4 + 3];
        }
        o2[((size_t)r * 2 + mo) * DD + lane] = __float2half(acc);
    }
}

__global__ void k_gemm_id(const float* __restrict__ x, const float* __restrict__ W,
                          __half* __restrict__ hout, float* __restrict__ xnorm) {
    __shared__ float rowbuf[4][DD];
    int t = threadIdx.x, wib = t >> 6, lane = t & 63;
    float Wc[DD];
#pragma unroll
    for (int k = 0; k < DD; k++) Wc[k] = W[k * DD + lane];
    for (int r = blockIdx.x * 4 + wib; r < NN; r += gridDim.x * 4) {
        float xv = x[(size_t)r * DD + lane];
        float n = sqrtf(wsum(xv * xv));
        xv /= fmaxf(n, 1e-12f);
        xnorm[(size_t)r * DD + lane] = xv;
        rowbuf[wib][lane] = xv;
        asm volatile("s_waitcnt lgkmcnt(0)" ::: "memory");
        float acc = 0.f;
#pragma unroll
        for (int k4 = 0; k4 < DD / 4; k4++) {
            float4 xq = *(const float4*)&rowbuf[wib][k4 * 4];
            acc += xq.x * Wc[k4 * 4] + xq.y * Wc[k4 * 4 + 1] + xq.z * Wc[k4 * 4 + 2] +
                   xq.w * Wc[k4 * 4 + 3];
        }
        hout[(size_t)r * DD + lane] = __float2half(acc);
    }
}

// ---------------- edge gate factors ----------------
__device__ __forceinline__ float gatef(float ssum) {
    float gate = 1.f / (1.f + __expf(-0.5f * ssum));
    return gate > 0.5f ? gate : 1.f;
}

__global__ void k_edgedot3(const __half* __restrict__ M, const int* __restrict__ rp,
                           const int* __restrict__ col, __half* __restrict__ gf4) {
    int t = blockIdx.x * blockDim.x + threadIdx.x;
    int wv = t >> 6, lane = t & 63, nw = (gridDim.x * blockDim.x) >> 6;
    int g = lane >> 3, q = lane & 7;
    for (int w0 = wv; w0 < NN; w0 += nw) {
        int n = nodeperm(w0);
        int e0 = rp[n], e1 = rp[n + 1];
        if (e0 == e1) continue;
        const uint4* trow = (const uint4*)(M + (size_t)n * 192);
        uint4 tv = trow[q], ta = trow[q + 8], tt = trow[q + 16];
        for (int eb = e0 + g; eb < e1; eb += 8) {
            int sn = col[eb];
            const uint4* srow = (const uint4*)(M + (size_t)sn * 192);
            uint4 sv = srow[q], sa = srow[q + 8], st = srow[q + 16];
            float dv = dot8(tv, sv), da = dot8(ta, sa), dt = dot8(tt, st);
            dv = qsum8(dv);
            da = qsum8(da);
            dt = qsum8(dt);
            if (q == 0) {
                U2H p01, p2;
                p01.hh = __floats2half2_rn(gatef(da + dt), gatef(dv + dt));
                p2.hh = __floats2half2_rn(gatef(da + dv), 0.f);
                *(uint2*)(gf4 + (size_t)eb * 4) = make_uint2(p01.u, p2.u);
            }
        }
    }
}

// ---------------- fused 3-modality GAT pre (fp16 acc, gate folded) ----------------
__global__ void k_gat_pre3(const __half* __restrict__ h3, const __half* __restrict__ gf4,
                           const int* __restrict__ rp, const int* __restrict__ col,
                           __half* __restrict__ x3h) {
    int t = blockIdx.x * blockDim.x + threadIdx.x;
    int wv = t >> 6, lane = t & 63, nw = (gridDim.x * blockDim.x) >> 6;
    int g = lane >> 3, q = lane & 7;
    const __half2 z = __floats2half2_rn(0.f, 0.f);
    for (int w0 = wv; w0 < NN; w0 += nw) {
        int n = nodeperm(w0);
        int e0 = rp[n], e1 = rp[n + 1];
        const uint4* hrow = (const uint4*)(h3 + (size_t)n * 192);
        uint4 hd0 = hrow[q], hd1 = hrow[q + 8], hd2 = hrow[q + 16];
        float s0 = 0.f, s1 = 0.f, s2 = 0.f;
        __half2 a0[4] = {z, z, z, z}, a1[4] = {z, z, z, z}, a2[4] = {z, z, z, z};
        for (int eb = e0 + g; eb < e1; eb += 8) {
            int sn = col[eb];
            const uint4* srow = (const uint4*)(h3 + (size_t)sn * 192);
            uint4 v0 = srow[q], v1 = srow[q + 8], v2 = srow[q + 16];
            uint2 gv = *(const uint2*)(gf4 + (size_t)eb * 4);
            float d0 = dot8(hd0, v0), d1 = dot8(hd1, v1), d2 = dot8(hd2, v2);
            d0 = qsum8(d0);
            d1 = qsum8(d1);
            d2 = qsum8(d2);
            float2 g01 = __half22float2(uh(gv.x));
            float g2 = __half22float2(uh(gv.y)).x;
            float sc0 = d0 > 0.f ? d0 : 0.2f * d0;
            float sc1 = d1 > 0.f ? d1 : 0.2f * d1;
            float sc2 = d2 > 0.f ? d2 : 0.2f * d2;
            float p0 = __expf(sc0), p1 = __expf(sc1), p2 = __expf(sc2);
            s0 += p0;
            s1 += p1;
            s2 += p2;
            __half2 ph0 = __float2half2_rn(p0 * g01.x);
            __half2 ph1 = __float2half2_rn(p1 * g01.y);
            __half2 ph2 = __float2half2_rn(p2 * g2);
            a0[0] = __hfma2(ph0, uh(v0.x), a0[0]);
            a0[1] = __hfma2(ph0, uh(v0.y), a0[1]);
            a0[2] = __hfma2(ph0, uh(v0.z), a0[2]);
            a0[3] = __hfma2(ph0, uh(v0.w), a0[3]);
            a1[0] = __hfma2(ph1, uh(v1.x), a1[0]);
            a1[1] = __hfma2(ph1, uh(v1.y), a1[1]);
            a1[2] = __hfma2(ph1, uh(v1.z), a1[2]);
            a1[3] = __hfma2(ph1, uh(v1.w), a1[3]);
            a2[0] = __hfma2(ph2, uh(v2.x), a2[0]);
            a2[1] = __hfma2(ph2, uh(v2.y), a2[1]);
            a2[2] = __hfma2(ph2, uh(v2.z), a2[2]);
            a2[3] = __hfma2(ph2, uh(v2.w), a2[3]);
        }
        s0 = gsum8(s0);
        s1 = gsum8(s1);
        s2 = gsum8(s2);
#pragma unroll
        for (int j = 0; j < 4; j++) {
            a0[j] = h2rx(h2rx(h2rx(a0[j], 8), 16), 32);
            a1[j] = h2rx(h2rx(h2rx(a1[j], 8), 16), 32);
            a2[j] = h2rx(h2rx(h2rx(a2[j], 8), 16), 32);
        }
        float i0 = 1.f / (s0 + 1e-16f), i1 = 1.f / (s1 + 1e-16f), i2 = 1.f / (s2 + 1e-16f);
        float o0[8], o1[8], o2[8];
#pragma unroll
        for (int j = 0; j < 4; j++) {
            float2 f0 = __half22float2(a0[j]);
            float2 f1 = __half22float2(a1[j]);
            float2 f2 = __half22float2(a2[j]);
            o0[2 * j] = f0.x * i0;
            o0[2 * j + 1] = f0.y * i0;
            o1[2 * j] = f1.x * i1;
            o1[2 * j + 1] = f1.y * i1;
            o2[2 * j] = f2.x * i2;
            o2[2 * j + 1] = f2.y * i2;
        }
        float n0 = 0.f, n1 = 0.f, n2 = 0.f;
#pragma unroll
        for (int k = 0; k < 8; k++) {
            n0 += o0[k] * o0[k];
            n1 += o1[k] * o1[k];
            n2 += o2[k] * o2[k];
        }
        n0 = qsum8(n0);
        n1 = qsum8(n1);
        n2 = qsum8(n2);
        float r0 = 1.f / fmaxf(sqrtf(n0), 1e-12f);
        float r1 = 1.f / fmaxf(sqrtf(n1), 1e-12f);
        float r2 = 1.f / fmaxf(sqrtf(n2), 1e-12f);
        if (g == 0) {
            uint4* orow = (uint4*)(x3h + (size_t)n * 192);
            uint4 w0_, w1_, w2_;
            w0_.x = hu(__floats2half2_rn(o0[0] * r0, o0[1] * r0));
            w0_.y = hu(__floats2half2_rn(o0[2] * r0, o0[3] * r0));
            w0_.z = hu(__floats2half2_rn(o0[4] * r0, o0[5] * r0));
            w0_.w = hu(__floats2half2_rn(o0[6] * r0, o0[7] * r0));
            w1_.x = hu(__floats2half2_rn(o1[0] * r1, o1[1] * r1));
            w1_.y = hu(__floats2half2_rn(o1[2] * r1, o1[3] * r1));
            w1_.z = hu(__floats2half2_rn(o1[4] * r1, o1[5] * r1));
            w1_.w = hu(__floats2half2_rn(o1[6] * r1, o1[7] * r1));
            w2_.x = hu(__floats2half2_rn(o2[0] * r2, o2[1] * r2));
            w2_.y = hu(__floats2half2_rn(o2[2] * r2, o2[3] * r2));
            w2_.z = hu(__floats2half2_rn(o2[4] * r2, o2[5] * r2));
            w2_.w = hu(__floats2half2_rn(o2[6] * r2, o2[7] * r2));
            orow[q] = w0_;
            orow[q + 8] = w1_;
            orow[q + 16] = w2_;
        }
    }
}

// ---------------- fused 3-modality GAT ori (residual + l2norm) ----------------
__global__ void k_gat_ori3(const __half* __restrict__ h3, const __half* __restrict__ x3h,
                           const int* __restrict__ rp, const int* __restrict__ col,
                           __half* __restrict__ xout, float* __restrict__ fout) {
    int t = blockIdx.x * blockDim.x + threadIdx.x;
    int wv = t >> 6, lane = t & 63, nw = (gridDim.x * blockDim.x) >> 6;
    int g = lane >> 3, q = lane & 7;
    const __half2 z = __floats2half2_rn(0.f, 0.f);
    for (int w0 = wv; w0 < NN; w0 += nw) {
        int n = nodeperm(w0);
        int e0 = rp[n], e1 = rp[n + 1];
        const uint4* hrow = (const uint4*)(h3 + (size_t)n * 192);
        uint4 hd0 = hrow[q], hd1 = hrow[q + 8], hd2 = hrow[q + 16];
        float s0 = 0.f, s1 = 0.f, s2 = 0.f;
        __half2 a0[4] = {z, z, z, z}, a1[4] = {z, z, z, z}, a2[4] = {z, z, z, z};
        for (int eb = e0 + g; eb < e1; eb += 8) {
            int sn = col[eb];
            const uint4* srow = (const uint4*)(h3 + (size_t)sn * 192);
            uint4 v0 = srow[q], v1 = srow[q + 8], v2 = srow[q + 16];
            float d0 = dot8(hd0, v0), d1 = dot8(hd1, v1), d2 = dot8(hd2, v2);
            d0 = qsum8(d0);
            d1 = qsum8(d1);
            d2 = qsum8(d2);
            float sc0 = d0 > 0.f ? d0 : 0.2f * d0;
            float sc1 = d1 > 0.f ? d1 : 0.2f * d1;
            float sc2 = d2 > 0.f ? d2 : 0.2f * d2;
            float p0 = __expf(sc0), p1 = __expf(sc1), p2 = __expf(sc2);
            s0 += p0;
            s1 += p1;
            s2 += p2;
            __half2 ph0 = __float2half2_rn(p0);
            __half2 ph1 = __float2half2_rn(p1);
            __half2 ph2 = __float2half2_rn(p2);
            a0[0] = __hfma2(ph0, uh(v0.x), a0[0]);
            a0[1] = __hfma2(ph0, uh(v0.y), a0[1]);
            a0[2] = __hfma2(ph0, uh(v0.z), a0[2]);
            a0[3] = __hfma2(ph0, uh(v0.w), a0[3]);
            a1[0] = __hfma2(ph1, uh(v1.x), a1[0]);
            a1[1] = __hfma2(ph1, uh(v1.y), a1[1]);
            a1[2] = __hfma2(ph1, uh(v1.z), a1[2]);
            a1[3] = __hfma2(ph1, uh(v1.w), a1[3]);
            a2[0] = __hfma2(ph2, uh(v2.x), a2[0]);
            a2[1] = __hfma2(ph2, uh(v2.y), a2[1]);
            a2[2] = __hfma2(ph2, uh(v2.z), a2[2]);
            a2[3] = __hfma2(ph2, uh(v2.w), a2[3]);
        }
        s0 = gsum8(s0);
        s1 = gsum8(s1);
        s2 = gsum8(s2);
#pragma unroll
        for (int j = 0; j < 4; j++) {
            a0[j] = h2rx(h2rx(h2rx(a0[j], 8), 16), 32);
            a1[j] = h2rx(h2rx(h2rx(a1[j], 8), 16), 32);
            a2[j] = h2rx(h2rx(h2rx(a2[j], 8), 16), 32);
        }
        float i0 = 1.f / (s0 + 1e-16f), i1 = 1.f / (s1 + 1e-16f), i2 = 1.f / (s2 + 1e-16f);
        const uint4* xrow = (const uint4*)(x3h + (size_t)n * 192);
        uint4 xr0 = xrow[q], xr1 = xrow[q + 8], xr2 = xrow[q + 16];
        float o0[8], o1[8], o2[8];
#pragma unroll
        for (int j = 0; j < 4; j++) {
            float2 f0 = __half22float2(a0[j]);
            float2 f1 = __half22float2(a1[j]);
            float2 f2 = __half22float2(a2[j]);
            float2 xf0 = __half22float2(uh(j == 0 ? xr0.x : j == 1 ? xr0.y : j == 2 ? xr0.z : xr0.w));
            float2 xf1 = __half22float2(uh(j == 0 ? xr1.x : j == 1 ? xr1.y : j == 2 ? xr1.z : xr1.w));
            float2 xf2 = __half22float2(uh(j == 0 ? xr2.x : j == 1 ? xr2.y : j == 2 ? xr2.z : xr2.w));
            o0[2 * j] = xf0.x + f0.x * i0;
            o0[2 * j + 1] = xf0.y + f0.y * i0;
            o1[2 * j] = xf1.x + f1.x * i1;
            o1[2 * j + 1] = xf1.y + f1.y * i1;
            o2[2 * j] = xf2.x + f2.x * i2;
            o2[2 * j + 1] = xf2.y + f2.y * i2;
        }
        float n0 = 0.f, n1 = 0.f, n2 = 0.f;
#pragma unroll
        for (int k = 0; k < 8; k++) {
            n0 += o0[k] * o0[k];
            n1 += o1[k] * o1[k];
            n2 += o2[k] * o2[k];
        }
        n0 = qsum8(n0);
        n1 = qsum8(n1);
        n2 = qsum8(n2);
        float r0 = 1.f / fmaxf(sqrtf(n0), 1e-12f);
        float r1 = 1.f / fmaxf(sqrtf(n1), 1e-12f);
        float r2 = 1.f / fmaxf(sqrtf(n2), 1e-12f);
        if (g == 0) {
            if (fout) {
                float* ob = fout + (size_t)n * 256 + 64 + q * 8;
                float4 wa, wb;
                wa = make_float4(o0[0] * r0, o0[1] * r0, o0[2] * r0, o0[3] * r0);
                wb = make_float4(o0[4] * r0, o0[5] * r0, o0[6] * r0, o0[7] * r0);
                *(float4*)(ob) = wa;
                *(float4*)(ob + 4) = wb;
                wa = make_float4(o1[0] * r1, o1[1] * r1, o1[2] * r1, o1[3] * r1);
                wb = make_float4(o1[4] * r1, o1[5] * r1, o1[6] * r1, o1[7] * r1);
                *(float4*)(ob + 64) = wa;
                *(float4*)(ob + 68) = wb;
                wa = make_float4(o2[0] * r2, o2[1] * r2, o2[2] * r2, o2[3] * r2);
                wb = make_float4(o2[4] * r2, o2[5] * r2, o2[6] * r2, o2[7] * r2);
                *(float4*)(ob + 128) = wa;
                *(float4*)(ob + 132) = wb;
            } else {
                uint4* orow = (uint4*)(xout + (size_t)n * 192);
                uint4 w0_, w1_, w2_;
                w0_.x = hu(__floats2half2_rn(o0[0] * r0, o0[1] * r0));
                w0_.y = hu(__floats2half2_rn(o0[2] * r0, o0[3] * r0));
                w0_.z = hu(__floats2half2_rn(o0[4] * r0, o0[5] * r0));
                w0_.w = hu(__floats2half2_rn(o0[6] * r0, o0[7] * r0));
                w1_.x = hu(__floats2half2_rn(o1[0] * r1, o1[1] * r1));
                w1_.y = hu(__floats2half2_rn(o1[2] * r1, o1[3] * r1));
                w1_.z = hu(__floats2half2_rn(o1[4] * r1, o1[5] * r1));
                w1_.w = hu(__floats2half2_rn(o1[6] * r1, o1[7] * r1));
                w2_.x = hu(__floats2half2_rn(o2[0] * r2, o2[1] * r2));
                w2_.y = hu(__floats2half2_rn(o2[2] * r2, o2[3] * r2));
                w2_.z = hu(__floats2half2_rn(o2[4] * r2, o2[5] * r2));
                w2_.w = hu(__floats2half2_rn(o2[6] * r2, o2[7] * r2));
                orow[q] = w0_;
                orow[q + 8] = w1_;
                orow[q + 16] = w2_;
            }
        }
    }
}

// ---------------- GCN ----------------
__global__ void k_gcn1(const __half* __restrict__ h, const int* __restrict__ rp,
                       const int* __restrict__ col, float* __restrict__ out) {
    int t = blockIdx.x * blockDim.x + threadIdx.x;
    int wv = t >> 6, lane = t & 63, nw = (gridDim.x * blockDim.x) >> 6;
    int g = lane >> 3, q = lane & 7;
    const __half2 z = __floats2half2_rn(0.f, 0.f);
    for (int w0 = wv; w0 < NN; w0 += nw) {
        int n = nodeperm(w0);
        int e0 = rp[n], e1 = rp[n + 1];
        __half2 a[4] = {z, z, z, z};
        for (int eb = e0 + g; eb < e1; eb += 8) {
            int sn = col[eb];
            uint4 v = ((const uint4*)(h + (size_t)sn * DD))[q];
            a[0] = __hadd2(a[0], uh(v.x));
            a[1] = __hadd2(a[1], uh(v.y));
            a[2] = __hadd2(a[2], uh(v.z));
            a[3] = __hadd2(a[3], uh(v.w));
        }
#pragma unroll
        for (int j = 0; j < 4; j++) a[j] = h2rx(h2rx(h2rx(a[j], 8), 16), 32);
        if (g == 0) {
            float o[8];
#pragma unroll
            for (int j = 0; j < 4; j++) {
                float2 f = __half22float2(a[j]);
                o[2 * j] = f.x > 0.f ? f.x : 0.01f * f.x;
                o[2 * j + 1] = f.y > 0.f ? f.y : 0.01f * f.y;
            }
            float* ob = out + (size_t)n * DD + q * 8;
            *(float4*)(ob) = make_float4(o[0], o[1], o[2], o[3]);
            *(float4*)(ob + 4) = make_float4(o[4], o[5], o[6], o[7]);
        }
    }
}

__global__ void k_gcn_final2(const __half* __restrict__ gp, const int* __restrict__ rp,
                             const int* __restrict__ col, const float* __restrict__ x0,
                             const float* __restrict__ h1, float* __restrict__ out) {
    int t = blockIdx.x * blockDim.x + threadIdx.x;
    int wv = t >> 6, lane = t & 63, nw = (gridDim.x * blockDim.x) >> 6;
    int g = lane >> 3, q = lane & 7;
    const __half2 z = __floats2half2_rn(0.f, 0.f);
    for (int w0 = wv; w0 < NN; w0 += nw) {
        int n = nodeperm(w0);
        int e0 = rp[n], e1 = rp[n + 1];
        __half2 aA[4] = {z, z, z, z}, aB[4] = {z, z, z, z};
        for (int eb = e0 + g; eb < e1; eb += 8) {
            int sn = col[eb];
            const uint4* base = (const uint4*)(gp + (size_t)sn * 128);
            uint4 vA = base[q], vB = base[q + 8];
            aA[0] = __hadd2(aA[0], uh(vA.x));
            aA[1] = __hadd2(aA[1], uh(vA.y));
            aA[2] = __hadd2(aA[2], uh(vA.z));
            aA[3] = __hadd2(aA[3], uh(vA.w));
            aB[0] = __hadd2(aB[0], uh(vB.x));
            aB[1] = __hadd2(aB[1], uh(vB.y));
            aB[2] = __hadd2(aB[2], uh(vB.z));
            aB[3] = __hadd2(aB[3], uh(vB.w));
        }
#pragma unroll
        for (int j = 0; j < 4; j++) {
            aA[j] = h2rx(h2rx(h2rx(aA[j], 8), 16), 32);
            aB[j] = h2rx(h2rx(h2rx(aB[j], 8), 16), 32);
        }
        if (g == 0) {
            const float* p0 = x0 + (size_t)n * DD + q * 8;
            const float* p1 = h1 + (size_t)n * DD + q * 8;
            float4 v0a = *(const float4*)(p0), v0b = *(const float4*)(p0 + 4);
            float4 v1a = *(const float4*)(p1), v1b = *(const float4*)(p1 + 4);
            float o[8];
#pragma unroll
            for (int j = 0; j < 4; j++) {
                float2 fA = __half22float2(aA[j]);
                float2 fB = __half22float2(aB[j]);
                float h2x = fA.x > 0.f ? fA.x : 0.01f * fA.x;
                float h2y = fA.y > 0.f ? fA.y : 0.01f * fA.y;
                o[2 * j] = h2x + fB.x;
                o[2 * j + 1] = h2y + fB.y;
            }
            float* ob = out + (size_t)n * 256 + q * 8;
            *(float4*)(ob) = make_float4(o[0] + v0a.x + v1a.x, o[1] + v0a.y + v1a.y,
                                         o[2] + v0a.z + v1a.z, o[3] + v0a.w + v1a.w);
            *(float4*)(ob + 4) = make_float4(o[4] + v0b.x + v1b.x, o[5] + v0b.y + v1b.y,
                                             o[6] + v0b.z + v1b.z, o[7] + v0b.w + v1b.w);
        }
    }
}

extern "C" void kernel_launch(void* const* d_in, const int* in_sizes, int n_in,
                              void* d_out, int out_size, void* d_ws, size_t ws_size,
                              hipStream_t stream) {
    const int* ei       = (const int*)d_in[0];
    const float* v_feat = (const float*)d_in[1];
    const float* a_feat = (const float*)d_in[2];
    const float* t_feat = (const float*)d_in[3];
    const float* pref_v = (const float*)d_in[4];
    const float* pref_a = (const float*)d_in[5];
    const float* pref_t = (const float*)d_in[6];
    const float* mlp_v_w = (const float*)d_in[7];
    const float* mlp_v_b = (const float*)d_in[8];
    const float* mlp_a_w = (const float*)d_in[9];
    const float* mlp_a_b = (const float*)d_in[10];
    const float* mlp_t_w = (const float*)d_in[11];
    const float* mlp_t_b = (const float*)d_in[12];
    const float* pre_w  = (const float*)d_in[13];
    const float* ori_w  = (const float*)d_in[14];
    const float* gcn_w  = (const float*)d_in[15];
    const float* id_emb = (const float*)d_in[16];
    float* out = (float*)d_out;

    const int E2 = in_sizes[0];
    const int E  = E2 / 2;

    char* w = (char*)d_ws;
    auto alloc = [&](size_t bytes) -> void* {
        void* p = (void*)w;
        w += (bytes + 255) & ~(size_t)255;
        return p;
    };
    int* cnt  = (int*)alloc((size_t)NN * 4);
    int* rp   = (int*)alloc((size_t)(NN + 1) * 4);
    int* bsum = (int*)alloc(256);
    int* col  = (int*)alloc((size_t)E2 * 4);
    __half* Mh3  = (__half*)alloc(3 * PLANE * 2);
    __half* hb3h = (__half*)alloc(3 * PLANE * 2);
    __half* x3h  = (__half*)alloc(3 * PLANE * 2);
    __half* gf4  = (__half*)alloc((size_t)E2 * 4 * 2);
    float* x0f = (float*)alloc(PLANE * 4);
    float* h1f = (float*)alloc(PLANE * 4);

    __half* g1 = hb3h;
    __half* gpair = hb3h + PLANE;

    // ---- CSR by destination ----
    const int NBLK = 64, CHUNK = (NN + NBLK - 1) / NBLK;
    hipMemsetAsync(cnt, 0, (size_t)NN * 4, stream);
    k_hist<<<(E2 + 255) / 256, 256, 0, stream>>>(ei, E2, E, cnt);
    k_bsum<<<NBLK, 256, 0, stream>>>(cnt, bsum, NN, CHUNK);
    k_bscan<<<1, 64, 0, stream>>>(bsum, NBLK, rp + NN);
    k_apply<<<NBLK, 256, 0, stream>>>(cnt, bsum, rp, NN, CHUNK);
    hipMemsetAsync(cnt, 0, (size_t)NN * 4, stream);
    k_scatter<<<(E2 + 255) / 256, 256, 0, stream>>>(ei, E2, E, rp, cnt, col);

    // ---- node tables (interleaved fp16) ----
    k_prep_pref<<<640, 256, 0, stream>>>(pref_v, pref_a, pref_t, Mh3);
    k_mlp<128><<<1024, 256, 0, stream>>>(v_feat, mlp_v_w, mlp_v_b, Mh3, 0);
    k_mlp<128><<<1024, 256, 0, stream>>>(a_feat, mlp_a_w, mlp_a_b, Mh3, 1);
    k_mlp<100><<<1024, 256, 0, stream>>>(t_feat, mlp_t_w, mlp_t_b, Mh3, 2);

    const int GB = (NN + 3) / 4;

    // ---- cross-modal gates ----
    k_edgedot3<<<GB, 256, 0, stream>>>(Mh3, rp, col, gf4);

    // ---- 3-modality chains ----
    dim3 g3(1280, 3);
    k_gemm_h3<<<g3, 256, 0, stream>>>(Mh3, pre_w, hb3h);
    k_gat_pre3<<<GB, 256, 0, stream>>>(hb3h, gf4, rp, col, x3h);
    for (int it = 0; it < 3; it++) {
        k_gemm_h3<<<g3, 256, 0, stream>>>(x3h, ori_w, hb3h);
        if (it < 2)
            k_gat_ori3<<<GB, 256, 0, stream>>>(hb3h, x3h, rp, col, x3h, nullptr);
        else
            k_gat_ori3<<<GB, 256, 0, stream>>>(hb3h, x3h, rp, col, nullptr, out);
    }

    // ---- real_gcn ----
    k_gemm_id<<<1280, 256, 0, stream>>>(id_emb, gcn_w, g1, x0f);
    k_gcn1<<<GB, 256, 0, stream>>>(g1, rp, col, h1f);
    dim3 g2(1280, 2);
    k_gemm_f2<<<g2, 256, 0, stream>>>(h1f, gcn_w + 4096, gpair);
    k_gcn_final2<<<GB, 256, 0, stream>>>(gpair, rp, col, x0f, h1f, out);
}